// Round 3
// 836.115 us; speedup vs baseline: 1.0082x; 1.0082x over previous
//
#include <hip/hip_runtime.h>
#include <cmath>

// Problem constants (fixed by reference setup)
#define NTOK 4096            // B*S = 2*2048
#define HD   4096            // hidden dim
#define NE   8               // experts
#define CAP  1536            // int(B*S*1.5*2/8)
#define NSEL 8192            // NTOK * TOP_K
#define TAU  2.5e-3f         // near-tie gap threshold (fp16 gemm: sigma~4.4e-4 -> 5.7 sigma)
#define MAXFLAG 256
#define GSIZE 32             // flagged tokens per W1 pass in stageA

// d_out layout (float element offsets)
#define COMB_OFF  50331648UL   // NTOK*NE*CAP
#define PROBS_OFF 100663296UL  // 2*NTOK*NE*CAP
#define AUX_OFF   100696064UL  // PROBS_OFF + NTOK*NE
#define HFLAG_OFF 25165824UL   // hflag scratch inside dispatch region (4 MB)

typedef unsigned short ushort_t;
typedef _Float16 half_t;
typedef half_t half8 __attribute__((ext_vector_type(8)));
typedef float floatx16 __attribute__((ext_vector_type(16)));

// Panel format: [group g (32 rows)][kstep ks (32 k)][2048 bytes]; 16B chunk u:
// h=u>>6, l=u&63, r=l&31, oh=l>>5 -> (row r, k=h*16+oh*8+j). Staging: lane l
// sources chunk l / 64+l -> each global_load_lds = one contiguous 1KB burst.

// ---- async 16B global->LDS (gsrc per-lane; lds dest = base+lane*16) ------
__device__ __forceinline__ void async_copy16(const void* g, void* l) {
    __builtin_amdgcn_global_load_lds(
        (const __attribute__((address_space(1))) unsigned int*)g,
        (__attribute__((address_space(3))) unsigned int*)l, 16, 0, 0);
}

// ---------------- Kernel 1: x -> fp16 panels ------------------------------
// grid (128 g, 32 q); block covers rows g*32..+32, k = q*128..+128.
__global__ __launch_bounds__(256) void convert_x_panel(
    const float* __restrict__ x, ushort_t* __restrict__ xp)
{
    __shared__ float xs[32 * 128];      // 16 KB
    const int g = blockIdx.x, q = blockIdx.y, t = threadIdx.x;
#pragma unroll
    for (int i = 0; i < 4; ++i) {
        int idx = i * 256 + t;
        int row = idx >> 5, c4 = (idx & 31) * 4;
        float4 v = *(const float4*)(x + (size_t)(g * 32 + row) * HD + q * 128 + c4);
        *(float4*)(&xs[row * 128 + c4]) = v;
    }
    __syncthreads();
#pragma unroll
    for (int it = 0; it < 2; ++it) {
        int c = it * 256 + t;
        int s = c >> 7, u = c & 127;
        int h = u >> 6, l = u & 63, r = l & 31, oh = l >> 5;
        int kl = s * 32 + h * 16 + oh * 8;
        half8 h8;
#pragma unroll
        for (int j = 0; j < 8; ++j) h8[j] = (half_t)xs[r * 128 + kl + j];
        size_t off = ((size_t)(g * 128 + q * 4 + s)) * 1024 + u * 8;
        *(half8*)(xp + off) = h8;
    }
}

// ---------------- Kernel 2: W1 -> W1^T fp16 panels (transpose) ------------
__global__ __launch_bounds__(256) void convert_w1_panel(
    const float* __restrict__ W1, ushort_t* __restrict__ wp)
{
    __shared__ float ws[32 * 129];      // padded transpose stage
    const int gn = blockIdx.x, q = blockIdx.y, t = threadIdx.x;
#pragma unroll
    for (int i = 0; i < 4; ++i) {
        int idx = i * 256 + t;
        int kr = idx >> 3, c4 = (idx & 7) * 4;
        float4 v = *(const float4*)(W1 + (size_t)(q * 128 + kr) * HD + gn * 32 + c4);
        ws[(c4 + 0) * 129 + kr] = v.x;
        ws[(c4 + 1) * 129 + kr] = v.y;
        ws[(c4 + 2) * 129 + kr] = v.z;
        ws[(c4 + 3) * 129 + kr] = v.w;
    }
    __syncthreads();
#pragma unroll
    for (int it = 0; it < 2; ++it) {
        int c = it * 256 + t;
        int s = c >> 7, u = c & 127;
        int h = u >> 6, l = u & 63, r = l & 31, oh = l >> 5;
        int kl = s * 32 + h * 16 + oh * 8;
        half8 h8;
#pragma unroll
        for (int j = 0; j < 8; ++j) h8[j] = (half_t)ws[r * 129 + kl + j];
        size_t off = ((size_t)(gn * 128 + q * 4 + s)) * 1024 + u * 8;
        *(half8*)(wp + off) = h8;
    }
}

// ---------------- Kernel 3: h = relu(x@W1 + b1), 8-phase fp16 GEMM --------
// 256x256 tile, BK=64, 8 waves (2M x 4N), 512 threads, wave tile 128x64 =
// 4x2 of 32x32. LDS: 2 dbuf x 64KB (A 32KB + B 32KB), unit (g,ksu)=1024
// ushorts at (g*2+ksu)*1024 (B at +16384). Per K-tile each wave stages its
// own group g=wave: 8 global_load_lds (2/phase); counted s_waitcnt vmcnt(4)
// at ends of phases 1 and 3 only (4 loads stay in flight across barriers).
// Raw s_barrier (NOT __syncthreads - that drains vmcnt(0) = the ~900TF
// ceiling). sched_barrier(0) after each barrier pins the schedule (rule 18).

#define MFMA8() do { \
    acc[0][0] = __builtin_amdgcn_mfma_f32_32x32x16_f16(ah0, bh0, acc[0][0], 0, 0, 0); \
    acc[0][1] = __builtin_amdgcn_mfma_f32_32x32x16_f16(ah0, bh1, acc[0][1], 0, 0, 0); \
    acc[1][0] = __builtin_amdgcn_mfma_f32_32x32x16_f16(ah1, bh0, acc[1][0], 0, 0, 0); \
    acc[1][1] = __builtin_amdgcn_mfma_f32_32x32x16_f16(ah1, bh1, acc[1][1], 0, 0, 0); \
    acc[2][0] = __builtin_amdgcn_mfma_f32_32x32x16_f16(ah2, bh0, acc[2][0], 0, 0, 0); \
    acc[2][1] = __builtin_amdgcn_mfma_f32_32x32x16_f16(ah2, bh1, acc[2][1], 0, 0, 0); \
    acc[3][0] = __builtin_amdgcn_mfma_f32_32x32x16_f16(ah3, bh0, acc[3][0], 0, 0, 0); \
    acc[3][1] = __builtin_amdgcn_mfma_f32_32x32x16_f16(ah3, bh1, acc[3][1], 0, 0, 0); \
} while (0)

#define LDA(mi, ks) (*(const half8*)&lds[cur * 32768 + ((wm * 4 + (mi)) * 2 + ((ks) >> 1)) * 1024 + ((ks) & 1) * 512 + lsrc])
#define LDB(ni, ks) (*(const half8*)&lds[cur * 32768 + 16384 + ((wn * 2 + (ni)) * 2 + ((ks) >> 1)) * 1024 + ((ks) & 1) * 512 + lsrc])

#define STAGE_A(c, kt, ksu) do { \
    const ushort_t* s_ = srcA + ((size_t)((kt) * 2 + (ksu))) * 1024; \
    ushort_t* d_ = lds + (c) * 32768 + (wave * 2 + (ksu)) * 1024; \
    async_copy16(s_, d_); async_copy16(s_ + 512, d_ + 512); \
} while (0)

#define STAGE_B(c, kt, ksu) do { \
    const ushort_t* s_ = srcB + ((size_t)((kt) * 2 + (ksu))) * 1024; \
    ushort_t* d_ = lds + (c) * 32768 + 16384 + (wave * 2 + (ksu)) * 1024; \
    async_copy16(s_, d_); async_copy16(s_ + 512, d_ + 512); \
} while (0)

#define STAGE_NONE do {} while (0)
#define VM4 asm volatile("s_waitcnt vmcnt(4)" ::: "memory")
#define VM0 asm volatile("s_waitcnt vmcnt(0)" ::: "memory")
#define TW_NONE do {} while (0)

#define PHASE(ks, STG, TW) do { \
    half8 ah0 = LDA(0, ks), ah1 = LDA(1, ks), ah2 = LDA(2, ks), ah3 = LDA(3, ks); \
    half8 bh0 = LDB(0, ks), bh1 = LDB(1, ks); \
    STG; \
    __builtin_amdgcn_s_barrier(); \
    asm volatile("s_waitcnt lgkmcnt(0)" ::: "memory"); \
    __builtin_amdgcn_sched_barrier(0); \
    __builtin_amdgcn_s_setprio(1); \
    MFMA8(); \
    __builtin_amdgcn_s_setprio(0); \
    TW; \
    __builtin_amdgcn_s_barrier(); \
    __builtin_amdgcn_sched_barrier(0); \
} while (0)

__global__ __launch_bounds__(512, 2) void gemm16_8phase(
    const ushort_t* __restrict__ Ap, const ushort_t* __restrict__ Bp,
    const float* __restrict__ bias,
    float* __restrict__ C)
{
    __shared__ __attribute__((aligned(16))) ushort_t lds[65536];  // 128 KB

    const int tid  = threadIdx.x;
    const int wave = tid >> 6;
    const int lane = tid & 63;
    const int l31  = lane & 31;
    const int lh   = lane >> 5;
    const int m0 = blockIdx.y * 256;
    const int n0 = blockIdx.x * 256;
    const int wm = wave >> 2;        // 0..1 -> rows wm*128
    const int wn = wave & 3;         // 0..3 -> cols wn*64

    floatx16 acc[4][2];
#pragma unroll
    for (int mi = 0; mi < 4; ++mi)
#pragma unroll
        for (int ni = 0; ni < 2; ++ni)
#pragma unroll
            for (int r = 0; r < 16; ++r) acc[mi][ni][r] = 0.f;

    const int lsrc = lane * 8;       // 16 B per lane
    const ushort_t* srcA = Ap + ((size_t)(blockIdx.y * 8 + wave)) * 128 * 1024 + lsrc;
    const ushort_t* srcB = Bp + ((size_t)(blockIdx.x * 8 + wave)) * 128 * 1024 + lsrc;

    // Prologue: stage K-tile 0 fully, keep the last 4 loads in flight.
    STAGE_A(0, 0, 0); STAGE_B(0, 0, 0);
    STAGE_A(0, 0, 1); STAGE_B(0, 0, 1);
    VM4;
    __builtin_amdgcn_s_barrier();
    __builtin_amdgcn_sched_barrier(0);

    int cur = 0;
    for (int kt = 0; kt < 63; ++kt) {
        PHASE(0, STAGE_A(cur ^ 1, kt + 1, 0), TW_NONE);
        PHASE(1, STAGE_B(cur ^ 1, kt + 1, 0), VM4);
        PHASE(2, STAGE_A(cur ^ 1, kt + 1, 1), TW_NONE);
        PHASE(3, STAGE_B(cur ^ 1, kt + 1, 1), VM4);
        cur ^= 1;
    }
    // Peeled last K-tile (kt=63): no prefetch; single drain before H1 phases.
    PHASE(0, STAGE_NONE, TW_NONE);
    PHASE(1, STAGE_NONE, VM0);
    PHASE(2, STAGE_NONE, TW_NONE);
    PHASE(3, STAGE_NONE, TW_NONE);

    // Epilogue: bias + relu. C/D map: col = l31, row = (r&3)+8*(r>>2)+4*lh
    {
        const int ncol = n0 + wn * 64 + l31;
        const float b1v0 = bias[ncol];
        const float b1v1 = bias[ncol + 32];
#pragma unroll
        for (int mi = 0; mi < 4; ++mi) {
#pragma unroll
            for (int r = 0; r < 16; ++r) {
                int row = m0 + wm * 128 + mi * 32 + (r & 3) + 8 * (r >> 2) + 4 * lh;
                float* crow = C + (size_t)row * HD + ncol;
                float v0 = acc[mi][0][r] + b1v0;
                float v1 = acc[mi][1][r] + b1v1;
                crow[0]  = v0 > 0.f ? v0 : 0.f;
                crow[32] = v1 > 0.f ? v1 : 0.f;
            }
        }
    }
}

// ---------------- Kernel 4: logits = h @ W2 + b2 (fp32) ------------------
__global__ __launch_bounds__(256) void logits_kernel(
    const float* __restrict__ h, const float* __restrict__ W2,
    const float* __restrict__ b2, float* __restrict__ logits)
{
    const int t = blockIdx.x;
    const int tid = threadIdx.x;
    const float* hrow = h + (size_t)t * HD;

    float acc[NE];
#pragma unroll
    for (int e = 0; e < NE; ++e) acc[e] = 0.f;
    for (int f = tid; f < HD; f += 256) {
        float hv = hrow[f];
        float4 w0 = *(const float4*)(W2 + (size_t)f * NE);
        float4 w1 = *(const float4*)(W2 + (size_t)f * NE + 4);
        acc[0] += hv * w0.x; acc[1] += hv * w0.y; acc[2] += hv * w0.z; acc[3] += hv * w0.w;
        acc[4] += hv * w1.x; acc[5] += hv * w1.y; acc[6] += hv * w1.z; acc[7] += hv * w1.w;
    }
    __shared__ float red[256][NE];
#pragma unroll
    for (int e = 0; e < NE; ++e) red[tid][e] = acc[e];
    __syncthreads();
    for (int s = 128; s > 0; s >>= 1) {
        if (tid < s) {
#pragma unroll
            for (int e = 0; e < NE; ++e) red[tid][e] += red[tid + s][e];
        }
        __syncthreads();
    }
    if (tid < NE) logits[(size_t)t * NE + tid] = red[0][tid] + b2[tid];
}

// ---------------- Kernel 5: zero dispatch+combine (403 MB streaming) -----
__global__ __launch_bounds__(256) void zero_out_kernel(float* __restrict__ out)
{
    const int TOTALQ = 25165824;   // 2*NTOK*NE*CAP / 4
    int stride = gridDim.x * 256;
    float4 z = make_float4(0.f, 0.f, 0.f, 0.f);
    for (int q = blockIdx.x * 256 + threadIdx.x; q < TOTALQ; q += stride)
        ((float4*)out)[q] = z;
}

// ---------------- Kernel 5b: init count ----------------------------------
__global__ void init_count_kernel(int* __restrict__ count) { *count = 0; }

// ---------------- Kernel 5c: re-zero hflag residue (inside dispatch out) --
__global__ __launch_bounds__(256) void zero_hflag_kernel(float* __restrict__ hflag)
{
    int i = blockIdx.x * 256 + threadIdx.x;   // 1024 blocks: 262144 float4 = 4 MB
    ((float4*)hflag)[i] = make_float4(0.f, 0.f, 0.f, 0.f);
}

// ---------------- Kernel 6: flag near-ties, compact list -----------------
__global__ __launch_bounds__(256) void flag_compact_kernel(
    const float* __restrict__ logits, int* __restrict__ count, int* __restrict__ list)
{
    int t = blockIdx.x * 256 + threadIdx.x;
    float l[NE];
    *(float4*)(&l[0]) = *(const float4*)(logits + (size_t)t * NE);
    *(float4*)(&l[4]) = *(const float4*)(logits + (size_t)t * NE + 4);
    float a = -1e30f, b = -1e30f, c = -1e30f;
#pragma unroll
    for (int e = 0; e < NE; ++e) {
        float v = l[e];
        if (v > a) { c = b; b = a; a = v; }
        else if (v > b) { c = b; b = v; }
        else if (v > c) { c = v; }
    }
    if (b - c < TAU) {
        int p = atomicAdd(count, 1);
        if (p < MAXFLAG) list[p] = t;
    }
}

// ---------------- Kernel 7a: batched exact pre-activation h for flagged --
// grid (64 f-chunks, 4 k-splits); one W1 pass per 32 flagged tokens.
__global__ __launch_bounds__(256) void fixup_stageA(
    const float* __restrict__ x, const float* __restrict__ W1,
    const int* __restrict__ count_p, const int* __restrict__ list,
    float* __restrict__ hflag)
{
    __shared__ float xs[GSIZE][256];          // 32 KB
    __shared__ float red[4][GSIZE][64];       // 32 KB
    const int tid = threadIdx.x;
    const int fl  = tid & 63;
    const int kg  = tid >> 6;
    const int f   = blockIdx.x * 64 + fl;
    const int kbase = blockIdx.y * 1024;
    int count = *count_p;
    if (count > MAXFLAG) count = MAXFLAG;

    for (int g = 0; g * GSIZE < count; ++g) {
        const int gbase = g * GSIZE;
        int ntok = count - gbase; if (ntok > GSIZE) ntok = GSIZE;

        float acc[GSIZE];
#pragma unroll
        for (int t = 0; t < GSIZE; ++t) acc[t] = 0.f;

        for (int kb = 0; kb < 1024; kb += 256) {
            __syncthreads();
            for (int i = tid; i < ntok * 256; i += 256) {
                int t = i >> 8, kk = i & 255;
                xs[t][kk] = x[(size_t)list[gbase + t] * HD + kbase + kb + kk];
            }
            __syncthreads();
            for (int j = 0; j < 64; ++j) {
                int kk = kg * 64 + j;
                float w = W1[(size_t)(kbase + kb + kk) * HD + f];
#pragma unroll
                for (int t = 0; t < GSIZE; ++t) acc[t] += xs[t][kk] * w;
            }
        }
        __syncthreads();
#pragma unroll
        for (int t = 0; t < GSIZE; ++t) red[kg][t][fl] = acc[t];
        __syncthreads();
        if (kg == 0) {
            for (int t = 0; t < ntok; ++t) {
                float v = red[0][t][fl] + red[1][t][fl] + red[2][t][fl] + red[3][t][fl];
                atomicAdd(&hflag[(size_t)(gbase + t) * HD + f], v);
            }
        }
        __syncthreads();
    }
}

// ---------------- Kernel 7b: exact logits for flagged tokens -------------
__global__ __launch_bounds__(256) void fixup_stageB(
    const float* __restrict__ hflag, const float* __restrict__ b1,
    const float* __restrict__ W2, const float* __restrict__ b2,
    const int* __restrict__ count_p, const int* __restrict__ list,
    float* __restrict__ logits)
{
    int count = *count_p;
    if (count > MAXFLAG) count = MAXFLAG;
    const int b = blockIdx.x;
    if (b >= count) return;
    const int tok = list[b];
    const int tid = threadIdx.x;

    float acc[NE];
#pragma unroll
    for (int e = 0; e < NE; ++e) acc[e] = 0.f;
    for (int f = tid; f < HD; f += 256) {
        float hv = hflag[(size_t)b * HD + f] + b1[f];
        hv = hv > 0.f ? hv : 0.f;
        float4 w0 = *(const float4*)(W2 + (size_t)f * NE);
        float4 w1 = *(const float4*)(W2 + (size_t)f * NE + 4);
        acc[0] += hv * w0.x; acc[1] += hv * w0.y; acc[2] += hv * w0.z; acc[3] += hv * w0.w;
        acc[4] += hv * w1.x; acc[5] += hv * w1.y; acc[6] += hv * w1.z; acc[7] += hv * w1.w;
    }
    __shared__ float red[256][NE];
#pragma unroll
    for (int e = 0; e < NE; ++e) red[tid][e] = acc[e];
    __syncthreads();
    for (int s = 128; s > 0; s >>= 1) {
        if (tid < s) {
#pragma unroll
            for (int e = 0; e < NE; ++e) red[tid][e] += red[tid + s][e];
        }
        __syncthreads();
    }
    if (tid < NE) logits[(size_t)tok * NE + tid] = red[0][tid] + b2[tid];
}

// ---------------- Kernel 8: softmax + top2 + renorm + partial sums -------
__global__ __launch_bounds__(256) void softmax_top2_kernel(
    const float* __restrict__ logits, float* __restrict__ probs_out,
    float* __restrict__ top2prob, int* __restrict__ top2idx,
    float* __restrict__ partial)
{
    const int tid = threadIdx.x;
    const int t = blockIdx.x * 256 + tid;

    float l[NE];
    *(float4*)(&l[0]) = *(const float4*)(logits + (size_t)t * NE);
    *(float4*)(&l[4]) = *(const float4*)(logits + (size_t)t * NE + 4);

    float mx = l[0];
#pragma unroll
    for (int e = 1; e < NE; ++e) mx = fmaxf(mx, l[e]);
    float p[NE], sum = 0.f;
#pragma unroll
    for (int e = 0; e < NE; ++e) { p[e] = __expf(l[e] - mx); sum += p[e]; }
    float inv = 1.f / sum;
#pragma unroll
    for (int e = 0; e < NE; ++e) p[e] *= inv;

#pragma unroll
    for (int e = 0; e < NE; ++e) probs_out[(size_t)t * NE + e] = p[e];

    float b1v = -1e30f, b2v = -1e30f;
    int i1 = 0, i2 = 0;
#pragma unroll
    for (int e = 0; e < NE; ++e) {
        float v = l[e];
        if (v > b1v) { b2v = b1v; i2 = i1; b1v = v; i1 = e; }
        else if (v > b2v) { b2v = v; i2 = e; }
    }
    float p1 = 0.f, p2 = 0.f;
#pragma unroll
    for (int e = 0; e < NE; ++e) { if (e == i1) p1 = p[e]; if (e == i2) p2 = p[e]; }
    float s = p1 + p2 + 1e-8f;
    top2prob[2 * t]     = p1 / s;
    top2prob[2 * t + 1] = p2 / s;
    top2idx[2 * t]      = i1;
    top2idx[2 * t + 1]  = i2;

    __shared__ float red[256][NE];
#pragma unroll
    for (int e = 0; e < NE; ++e) red[tid][e] = p[e];
    __syncthreads();
    for (int sdx = 128; sdx > 0; sdx >>= 1) {
        if (tid < sdx) {
#pragma unroll
            for (int e = 0; e < NE; ++e) red[tid][e] += red[tid + sdx][e];
        }
        __syncthreads();
    }
    if (tid < NE) partial[blockIdx.x * NE + tid] = red[0][tid];
}

// ---------------- Kernel 9: sequential capacity scan + slot map + aux ----
__global__ __launch_bounds__(256) void scan_dispatch_kernel(
    const int* __restrict__ top2idx, const float* __restrict__ top2prob,
    const float* __restrict__ partial, int* __restrict__ slot_pos,
    float* __restrict__ slot_val, float* __restrict__ aux_out)
{
    const int tid = threadIdx.x;
    const int ITEMS = NSEL / 256;

    for (int i = tid; i < NTOK * NE; i += 256) { slot_pos[i] = -1; slot_val[i] = 0.f; }

    int cnt[NE];
#pragma unroll
    for (int e = 0; e < NE; ++e) cnt[e] = 0;
    const int base = tid * ITEMS;
    for (int j = 0; j < ITEMS; ++j) {
        int v = top2idx[base + j];
#pragma unroll
        for (int e = 0; e < NE; ++e) cnt[e] += (v == e);
    }

    __shared__ int scnt[256][NE];
    __shared__ int tot[NE];
#pragma unroll
    for (int e = 0; e < NE; ++e) scnt[tid][e] = cnt[e];
    __syncthreads();

    if (tid < NE) {
        int run = 0;
        for (int i = 0; i < 256; ++i) {
            int c = scnt[i][tid];
            scnt[i][tid] = run;
            run += c;
        }
        tot[tid] = run;
    }
    __syncthreads();

    int off[NE];
#pragma unroll
    for (int e = 0; e < NE; ++e) off[e] = scnt[tid][e];
    for (int j = 0; j < ITEMS; ++j) {
        int item = base + j;
        int v = top2idx[item];
        int pos = 0;
#pragma unroll
        for (int e = 0; e < NE; ++e) { if (v == e) { pos = off[e]; off[e]++; } }
        if (pos < CAP) {
            int tok = item >> 1;
            slot_pos[tok * NE + v] = pos;
            slot_val[tok * NE + v] = top2prob[item];
        }
    }

    if (tid == 0) {
        float aux = 0.f;
#pragma unroll
        for (int e = 0; e < NE; ++e) {
            float pp = 0.f;
            for (int b = 0; b < 16; ++b) pp += partial[b * NE + e];
            aux += (pp / (float)NTOK) * ((float)tot[e] / (float)NSEL);
        }
        aux_out[0] = aux * (float)NE;
    }
}

// ---------------- Kernel 10: sparse scatter into zeroed outputs ----------
__global__ __launch_bounds__(256) void scatter_kernel(
    const int* __restrict__ slot_pos, const float* __restrict__ slot_val,
    float* __restrict__ out)
{
    int i = blockIdx.x * 256 + threadIdx.x;   // tok*NE + e, 0..32767
    int sp = slot_pos[i];
    if (sp >= 0) {
        out[(size_t)i * CAP + sp] = 1.0f;
        out[COMB_OFF + (size_t)i * CAP + sp] = slot_val[i];
    }
}

// ---------------- host ---------------------------------------------------
extern "C" void kernel_launch(void* const* d_in, const int* in_sizes, int n_in,
                              void* d_out, int out_size, void* d_ws, size_t ws_size,
                              hipStream_t stream)
{
    const float* x  = (const float*)d_in[0];
    const float* W1 = (const float*)d_in[1];
    const float* b1 = (const float*)d_in[2];
    const float* W2 = (const float*)d_in[3];
    const float* b2 = (const float*)d_in[4];
    float* out = (float*)d_out;

    // Staging in d_out (zeroed by zero_out after consumption; hflag region
    // re-zeroed after fixup since it lives inside the graded dispatch output):
    ushort_t* xp  = (ushort_t*)(out);                   // fp16 panel, 33.5 MB
    ushort_t* wp  = (ushort_t*)(out + 8388608);         // fp16 panel, 33.5 MB
    float*    hflag = out + HFLAG_OFF;                  // MAXFLAG*HD (4 MB)
    float* hbuf = out + COMB_OFF;                       // h fp32, 67 MB

    // ws layout (float offsets)
    float* ws       = (float*)d_ws;
    float* logits   = ws;
    float* top2prob = ws + 32768;
    int*   top2idx  = (int*)(ws + 40960);
    float* partial  = ws + 49152;
    int*   slot_pos = (int*)(ws + 49280);
    float* slot_val = ws + 82048;
    int*   count    = (int*)(ws + 114816);
    int*   list     = (int*)(ws + 114817);

    convert_x_panel<<<dim3(128, 32), 256, 0, stream>>>(x, xp);
    convert_w1_panel<<<dim3(128, 32), 256, 0, stream>>>(W1, wp);
    gemm16_8phase<<<dim3(16, 16), 512, 0, stream>>>(xp, wp, b1, hbuf);
    logits_kernel<<<NTOK, 256, 0, stream>>>(hbuf, W2, b2, logits);
    // panels + hbuf consumed: zero the whole dispatch+combine region now
    // (also zero-inits hflag for stageA's atomicAdd)
    zero_out_kernel<<<8192, 256, 0, stream>>>(out);
    init_count_kernel<<<1, 1, 0, stream>>>(count);
    flag_compact_kernel<<<16, 256, 0, stream>>>(logits, count, list);
    fixup_stageA<<<dim3(64, 4), 256, 0, stream>>>(x, W1, count, list, hflag);
    fixup_stageB<<<MAXFLAG, 256, 0, stream>>>(hflag, b1, W2, b2, count, list, logits);
    // hflag consumed: erase its residue from the dispatch output BEFORE scatter
    zero_hflag_kernel<<<1024, 256, 0, stream>>>(hflag);
    softmax_top2_kernel<<<16, 256, 0, stream>>>(logits, out + PROBS_OFF, top2prob, top2idx, partial);
    scan_dispatch_kernel<<<1, 256, 0, stream>>>(top2idx, top2prob, partial, slot_pos, slot_val, out + AUX_OFF);
    scatter_kernel<<<128, 256, 0, stream>>>(slot_pos, slot_val, out);
}

// Round 4
// 811.027 us; speedup vs baseline: 1.0393x; 1.0309x over previous
//
#include <hip/hip_runtime.h>
#include <cmath>

// Problem constants (fixed by reference setup)
#define NTOK 4096            // B*S = 2*2048
#define HD   4096            // hidden dim
#define NE   8               // experts
#define CAP  1536            // int(B*S*1.5*2/8)
#define NSEL 8192            // NTOK * TOP_K
#define TAU  2.5e-3f         // near-tie gap threshold (fp16 gemm: sigma~4.4e-4 -> 5.7 sigma)
#define MAXFLAG 256
#define GSIZE 32             // flagged tokens per W1 pass in stageA

// d_out layout (float element offsets)
#define COMB_OFF  50331648UL   // NTOK*NE*CAP
#define PROBS_OFF 100663296UL  // 2*NTOK*NE*CAP
#define AUX_OFF   100696064UL  // PROBS_OFF + NTOK*NE
#define HFLAG_OFF 25165824UL   // hflag scratch inside dispatch region (4 MB)

typedef unsigned short ushort_t;
typedef _Float16 half_t;
typedef half_t half8 __attribute__((ext_vector_type(8)));
typedef float floatx16 __attribute__((ext_vector_type(16)));

// Panel format: [group g (32 rows)][kstep ks (32 k)][2048 bytes]; 16B chunk u:
// h=u>>6, l=u&63, r=l&31, oh=l>>5 -> (row r, k=h*16+oh*8+j). Staging: lane l
// sources chunk l / 64+l -> each global_load_lds = one contiguous 1KB burst.

// ---- async 16B global->LDS (gsrc per-lane; lds dest = base+lane*16) ------
__device__ __forceinline__ void async_copy16(const void* g, void* l) {
    __builtin_amdgcn_global_load_lds(
        (const __attribute__((address_space(1))) unsigned int*)g,
        (__attribute__((address_space(3))) unsigned int*)l, 16, 0, 0);
}

// ---------------- Kernel 1: x -> fp16 panels ------------------------------
// grid (128 g, 32 q); block covers rows g*32..+32, k = q*128..+128.
__global__ __launch_bounds__(256) void convert_x_panel(
    const float* __restrict__ x, ushort_t* __restrict__ xp)
{
    __shared__ float xs[32 * 128];      // 16 KB
    const int g = blockIdx.x, q = blockIdx.y, t = threadIdx.x;
#pragma unroll
    for (int i = 0; i < 4; ++i) {
        int idx = i * 256 + t;
        int row = idx >> 5, c4 = (idx & 31) * 4;
        float4 v = *(const float4*)(x + (size_t)(g * 32 + row) * HD + q * 128 + c4);
        *(float4*)(&xs[row * 128 + c4]) = v;
    }
    __syncthreads();
#pragma unroll
    for (int it = 0; it < 2; ++it) {
        int c = it * 256 + t;
        int s = c >> 7, u = c & 127;
        int h = u >> 6, l = u & 63, r = l & 31, oh = l >> 5;
        int kl = s * 32 + h * 16 + oh * 8;
        half8 h8;
#pragma unroll
        for (int j = 0; j < 8; ++j) h8[j] = (half_t)xs[r * 128 + kl + j];
        size_t off = ((size_t)(g * 128 + q * 4 + s)) * 1024 + u * 8;
        *(half8*)(xp + off) = h8;
    }
}

// ---------------- Kernel 2: W1 -> W1^T fp16 panels (transpose) ------------
__global__ __launch_bounds__(256) void convert_w1_panel(
    const float* __restrict__ W1, ushort_t* __restrict__ wp)
{
    __shared__ float ws[32 * 129];      // padded transpose stage
    const int gn = blockIdx.x, q = blockIdx.y, t = threadIdx.x;
#pragma unroll
    for (int i = 0; i < 4; ++i) {
        int idx = i * 256 + t;
        int kr = idx >> 3, c4 = (idx & 7) * 4;
        float4 v = *(const float4*)(W1 + (size_t)(q * 128 + kr) * HD + gn * 32 + c4);
        ws[(c4 + 0) * 129 + kr] = v.x;
        ws[(c4 + 1) * 129 + kr] = v.y;
        ws[(c4 + 2) * 129 + kr] = v.z;
        ws[(c4 + 3) * 129 + kr] = v.w;
    }
    __syncthreads();
#pragma unroll
    for (int it = 0; it < 2; ++it) {
        int c = it * 256 + t;
        int s = c >> 7, u = c & 127;
        int h = u >> 6, l = u & 63, r = l & 31, oh = l >> 5;
        int kl = s * 32 + h * 16 + oh * 8;
        half8 h8;
#pragma unroll
        for (int j = 0; j < 8; ++j) h8[j] = (half_t)ws[r * 129 + kl + j];
        size_t off = ((size_t)(gn * 128 + q * 4 + s)) * 1024 + u * 8;
        *(half8*)(wp + off) = h8;
    }
}

// ---------------- Kernel 3: fused h = relu(x@W1+b1), logits += h@W2 ------
// 256x256 tile, BK=64, 8 waves (2M x 4N), 512 threads, wave tile 128x64 =
// 4x2 of 32x32. LDS: 2 dbuf x 64KB (A 32KB + B 32KB), unit (g,ksu)=1024
// ushorts at (g*2+ksu)*1024 (B at +16384). Stage-early: both half-tiles of
// kt+1 issued in phases 0-1; counted waits vmcnt(8) @P1 / vmcnt(4) @P3 so
// every load has ~4 phases of latency slack and 8-12 loads stay in flight
// across barriers. Cross-wave visibility: each wave's own counted wait
// precedes the barrier that publishes its staged group. Raw s_barrier (NOT
// __syncthreads - that drains vmcnt(0)). sched_barrier(0) per rule 18.
// Epilogue: logits[row][e] += relu(h)*W2 via transposed LDS tile + per-wave
// column-slice reduce + 2048 atomics/block (no h materialization).

#define MFMA8() do { \
    acc[0][0] = __builtin_amdgcn_mfma_f32_32x32x16_f16(ah0, bh0, acc[0][0], 0, 0, 0); \
    acc[0][1] = __builtin_amdgcn_mfma_f32_32x32x16_f16(ah0, bh1, acc[0][1], 0, 0, 0); \
    acc[1][0] = __builtin_amdgcn_mfma_f32_32x32x16_f16(ah1, bh0, acc[1][0], 0, 0, 0); \
    acc[1][1] = __builtin_amdgcn_mfma_f32_32x32x16_f16(ah1, bh1, acc[1][1], 0, 0, 0); \
    acc[2][0] = __builtin_amdgcn_mfma_f32_32x32x16_f16(ah2, bh0, acc[2][0], 0, 0, 0); \
    acc[2][1] = __builtin_amdgcn_mfma_f32_32x32x16_f16(ah2, bh1, acc[2][1], 0, 0, 0); \
    acc[3][0] = __builtin_amdgcn_mfma_f32_32x32x16_f16(ah3, bh0, acc[3][0], 0, 0, 0); \
    acc[3][1] = __builtin_amdgcn_mfma_f32_32x32x16_f16(ah3, bh1, acc[3][1], 0, 0, 0); \
} while (0)

#define LDA(mi, ks) (*(const half8*)&lds[cur * 32768 + ((wm * 4 + (mi)) * 2 + ((ks) >> 1)) * 1024 + ((ks) & 1) * 512 + lsrc])
#define LDB(ni, ks) (*(const half8*)&lds[cur * 32768 + 16384 + ((wn * 2 + (ni)) * 2 + ((ks) >> 1)) * 1024 + ((ks) & 1) * 512 + lsrc])

#define STAGE_A(c, kt, ksu) do { \
    const ushort_t* s_ = srcA + ((size_t)((kt) * 2 + (ksu))) * 1024; \
    ushort_t* d_ = lds + (c) * 32768 + (wave * 2 + (ksu)) * 1024; \
    async_copy16(s_, d_); async_copy16(s_ + 512, d_ + 512); \
} while (0)

#define STAGE_B(c, kt, ksu) do { \
    const ushort_t* s_ = srcB + ((size_t)((kt) * 2 + (ksu))) * 1024; \
    ushort_t* d_ = lds + (c) * 32768 + 16384 + (wave * 2 + (ksu)) * 1024; \
    async_copy16(s_, d_); async_copy16(s_ + 512, d_ + 512); \
} while (0)

#define STAGE_AB(c, kt, ksu) do { STAGE_A(c, kt, ksu); STAGE_B(c, kt, ksu); } while (0)

#define STAGE_NONE do {} while (0)
#define VM8 asm volatile("s_waitcnt vmcnt(8)" ::: "memory")
#define VM4 asm volatile("s_waitcnt vmcnt(4)" ::: "memory")
#define VM0 asm volatile("s_waitcnt vmcnt(0)" ::: "memory")
#define TW_NONE do {} while (0)

#define PHASE(ks, STG, TW) do { \
    half8 ah0 = LDA(0, ks), ah1 = LDA(1, ks), ah2 = LDA(2, ks), ah3 = LDA(3, ks); \
    half8 bh0 = LDB(0, ks), bh1 = LDB(1, ks); \
    STG; \
    __builtin_amdgcn_s_barrier(); \
    asm volatile("s_waitcnt lgkmcnt(0)" ::: "memory"); \
    __builtin_amdgcn_sched_barrier(0); \
    __builtin_amdgcn_s_setprio(1); \
    MFMA8(); \
    __builtin_amdgcn_s_setprio(0); \
    TW; \
    __builtin_amdgcn_s_barrier(); \
    __builtin_amdgcn_sched_barrier(0); \
} while (0)

__global__ __launch_bounds__(512, 2) void gemm16_8phase(
    const ushort_t* __restrict__ Ap, const ushort_t* __restrict__ Bp,
    const float* __restrict__ bias, const float* __restrict__ W2,
    float* __restrict__ logits_out)
{
    __shared__ __attribute__((aligned(16))) ushort_t lds[65536];  // 128 KB

    const int tid  = threadIdx.x;
    const int wave = tid >> 6;
    const int lane = tid & 63;
    const int l31  = lane & 31;
    const int lh   = lane >> 5;
    const int m0 = blockIdx.y * 256;
    const int n0 = blockIdx.x * 256;
    const int wm = wave >> 2;        // 0..1 -> rows wm*128
    const int wn = wave & 3;         // 0..3 -> cols wn*64

    floatx16 acc[4][2];
#pragma unroll
    for (int mi = 0; mi < 4; ++mi)
#pragma unroll
        for (int ni = 0; ni < 2; ++ni)
#pragma unroll
            for (int r = 0; r < 16; ++r) acc[mi][ni][r] = 0.f;

    const int lsrc = lane * 8;       // 16 B per lane
    const ushort_t* srcA = Ap + ((size_t)(blockIdx.y * 8 + wave)) * 128 * 1024 + lsrc;
    const ushort_t* srcB = Bp + ((size_t)(blockIdx.x * 8 + wave)) * 128 * 1024 + lsrc;

    // Prologue: stage K-tile 0 fully, keep the last 4 loads in flight.
    STAGE_AB(0, 0, 0);
    STAGE_AB(0, 0, 1);
    VM4;
    __builtin_amdgcn_s_barrier();
    __builtin_amdgcn_sched_barrier(0);

    int cur = 0;
    for (int kt = 0; kt < 63; ++kt) {
        PHASE(0, STAGE_AB(cur ^ 1, kt + 1, 0), TW_NONE);
        PHASE(1, STAGE_AB(cur ^ 1, kt + 1, 1), VM8);
        PHASE(2, STAGE_NONE, TW_NONE);
        PHASE(3, STAGE_NONE, VM4);
        cur ^= 1;
    }
    // Peeled last K-tile (kt=63): no prefetch; single drain before H1 phases.
    PHASE(0, STAGE_NONE, TW_NONE);
    PHASE(1, STAGE_NONE, VM0);
    PHASE(2, STAGE_NONE, TW_NONE);
    PHASE(3, STAGE_NONE, TW_NONE);

    // ---- fused logits epilogue (reuses the 128 KB LDS; all loads drained,
    // final phase barrier passed => safe to overwrite) --------------------
    // Ls_T[col 0..255][row 0..63] pad 65 (floats 0..16639)
    // W2s[256][8]                       (floats 16640..18687)
    // Rs[wave][64][8] pad 9             (floats 18688..23295)
    float* Lf  = (float*)lds;
    float* W2s = Lf + 16640;
    float* Rs  = Lf + 18688;

    // cache W2 slice for this block's 256 columns: 2048 floats, contiguous
    ((float4*)W2s)[tid] = ((const float4*)(W2 + (size_t)n0 * NE))[tid];

    const int ncol = n0 + wn * 64 + l31;
    const float b1v0 = bias[ncol];
    const float b1v1 = bias[ncol + 32];
    const int lcol = wn * 64 + l31;
    const int lrow_base = wm * 32;

    for (int mi = 0; mi < 4; ++mi) {
        __syncthreads();   // prev mi consumed (and W2s visible on first iter)
#pragma unroll
        for (int r = 0; r < 16; ++r) {
            int lr = lrow_base + (r & 3) + 8 * (r >> 2) + 4 * lh;
            float v0 = acc[mi][0][r] + b1v0;
            float v1 = acc[mi][1][r] + b1v1;
            Lf[(lcol)      * 65 + lr] = v0 > 0.f ? v0 : 0.f;
            Lf[(lcol + 32) * 65 + lr] = v1 > 0.f ? v1 : 0.f;
        }
        __syncthreads();
        // wave w reduces cols w*32..+31 over all 64 rows (lane = row)
        float le[NE];
#pragma unroll
        for (int e = 0; e < NE; ++e) le[e] = 0.f;
        for (int c = 0; c < 32; ++c) {
            int col = wave * 32 + c;
            float hv = Lf[col * 65 + lane];
            float4 wa = *(const float4*)&W2s[col * 8];
            float4 wb = *(const float4*)&W2s[col * 8 + 4];
            le[0] += hv * wa.x; le[1] += hv * wa.y; le[2] += hv * wa.z; le[3] += hv * wa.w;
            le[4] += hv * wb.x; le[5] += hv * wb.y; le[6] += hv * wb.z; le[7] += hv * wb.w;
        }
#pragma unroll
        for (int e = 0; e < NE; ++e) Rs[(wave * 64 + lane) * 9 + e] = le[e];
        __syncthreads();
        {
            int rr = tid >> 3, e = tid & 7;      // 512 threads = 64 rows x 8 e
            float s = 0.f;
#pragma unroll
            for (int w = 0; w < 8; ++w) s += Rs[(w * 64 + rr) * 9 + e];
            int row_g = m0 + (rr >> 5) * 128 + mi * 32 + (rr & 31);
            atomicAdd(&logits_out[(size_t)row_g * NE + e], s);
        }
    }
}

// ---------------- Kernel 4: logits = b2 (init for gemm atomics) ----------
__global__ __launch_bounds__(256) void init_logits_kernel(
    const float* __restrict__ b2, float* __restrict__ logits)
{
    int t = blockIdx.x * 256 + threadIdx.x;   // 16 blocks x 256 = NTOK
    float4 v0 = *(const float4*)b2;
    float4 v1 = *(const float4*)(b2 + 4);
    float4* dst = (float4*)(logits + (size_t)t * NE);
    dst[0] = v0; dst[1] = v1;
}

// ---------------- Kernel 5: zero dispatch+combine (403 MB streaming) -----
__global__ __launch_bounds__(256) void zero_out_kernel(float* __restrict__ out)
{
    const int TOTALQ = 25165824;   // 2*NTOK*NE*CAP / 4
    int stride = gridDim.x * 256;
    float4 z = make_float4(0.f, 0.f, 0.f, 0.f);
    for (int q = blockIdx.x * 256 + threadIdx.x; q < TOTALQ; q += stride)
        ((float4*)out)[q] = z;
}

// ---------------- Kernel 5b: init count ----------------------------------
__global__ void init_count_kernel(int* __restrict__ count) { *count = 0; }

// ---------------- Kernel 5c: re-zero hflag residue (inside dispatch out) --
__global__ __launch_bounds__(256) void zero_hflag_kernel(float* __restrict__ hflag)
{
    int i = blockIdx.x * 256 + threadIdx.x;   // 1024 blocks: 262144 float4 = 4 MB
    ((float4*)hflag)[i] = make_float4(0.f, 0.f, 0.f, 0.f);
}

// ---------------- Kernel 6: flag near-ties, compact list -----------------
__global__ __launch_bounds__(256) void flag_compact_kernel(
    const float* __restrict__ logits, int* __restrict__ count, int* __restrict__ list)
{
    int t = blockIdx.x * 256 + threadIdx.x;
    float l[NE];
    *(float4*)(&l[0]) = *(const float4*)(logits + (size_t)t * NE);
    *(float4*)(&l[4]) = *(const float4*)(logits + (size_t)t * NE + 4);
    float a = -1e30f, b = -1e30f, c = -1e30f;
#pragma unroll
    for (int e = 0; e < NE; ++e) {
        float v = l[e];
        if (v > a) { c = b; b = a; a = v; }
        else if (v > b) { c = b; b = v; }
        else if (v > c) { c = v; }
    }
    if (b - c < TAU) {
        int p = atomicAdd(count, 1);
        if (p < MAXFLAG) list[p] = t;
    }
}

// ---------------- Kernel 7a: batched exact pre-activation h for flagged --
// grid (64 f-chunks, 4 k-splits); one W1 pass per 32 flagged tokens.
__global__ __launch_bounds__(256) void fixup_stageA(
    const float* __restrict__ x, const float* __restrict__ W1,
    const int* __restrict__ count_p, const int* __restrict__ list,
    float* __restrict__ hflag)
{
    __shared__ float xs[GSIZE][256];          // 32 KB
    __shared__ float red[4][GSIZE][64];       // 32 KB
    const int tid = threadIdx.x;
    const int fl  = tid & 63;
    const int kg  = tid >> 6;
    const int f   = blockIdx.x * 64 + fl;
    const int kbase = blockIdx.y * 1024;
    int count = *count_p;
    if (count > MAXFLAG) count = MAXFLAG;

    for (int g = 0; g * GSIZE < count; ++g) {
        const int gbase = g * GSIZE;
        int ntok = count - gbase; if (ntok > GSIZE) ntok = GSIZE;

        float acc[GSIZE];
#pragma unroll
        for (int t = 0; t < GSIZE; ++t) acc[t] = 0.f;

        for (int kb = 0; kb < 1024; kb += 256) {
            __syncthreads();
            for (int i = tid; i < ntok * 256; i += 256) {
                int t = i >> 8, kk = i & 255;
                xs[t][kk] = x[(size_t)list[gbase + t] * HD + kbase + kb + kk];
            }
            __syncthreads();
            for (int j = 0; j < 64; ++j) {
                int kk = kg * 64 + j;
                float w = W1[(size_t)(kbase + kb + kk) * HD + f];
#pragma unroll
                for (int t = 0; t < GSIZE; ++t) acc[t] += xs[t][kk] * w;
            }
        }
        __syncthreads();
#pragma unroll
        for (int t = 0; t < GSIZE; ++t) red[kg][t][fl] = acc[t];
        __syncthreads();
        if (kg == 0) {
            for (int t = 0; t < ntok; ++t) {
                float v = red[0][t][fl] + red[1][t][fl] + red[2][t][fl] + red[3][t][fl];
                atomicAdd(&hflag[(size_t)(gbase + t) * HD + f], v);
            }
        }
        __syncthreads();
    }
}

// ---------------- Kernel 7b: exact logits for flagged tokens -------------
__global__ __launch_bounds__(256) void fixup_stageB(
    const float* __restrict__ hflag, const float* __restrict__ b1,
    const float* __restrict__ W2, const float* __restrict__ b2,
    const int* __restrict__ count_p, const int* __restrict__ list,
    float* __restrict__ logits)
{
    int count = *count_p;
    if (count > MAXFLAG) count = MAXFLAG;
    const int b = blockIdx.x;
    if (b >= count) return;
    const int tok = list[b];
    const int tid = threadIdx.x;

    float acc[NE];
#pragma unroll
    for (int e = 0; e < NE; ++e) acc[e] = 0.f;
    for (int f = tid; f < HD; f += 256) {
        float hv = hflag[(size_t)b * HD + f] + b1[f];
        hv = hv > 0.f ? hv : 0.f;
        float4 w0 = *(const float4*)(W2 + (size_t)f * NE);
        float4 w1 = *(const float4*)(W2 + (size_t)f * NE + 4);
        acc[0] += hv * w0.x; acc[1] += hv * w0.y; acc[2] += hv * w0.z; acc[3] += hv * w0.w;
        acc[4] += hv * w1.x; acc[5] += hv * w1.y; acc[6] += hv * w1.z; acc[7] += hv * w1.w;
    }
    __shared__ float red[256][NE];
#pragma unroll
    for (int e = 0; e < NE; ++e) red[tid][e] = acc[e];
    __syncthreads();
    for (int s = 128; s > 0; s >>= 1) {
        if (tid < s) {
#pragma unroll
            for (int e = 0; e < NE; ++e) red[tid][e] += red[tid + s][e];
        }
        __syncthreads();
    }
    if (tid < NE) logits[(size_t)tok * NE + tid] = red[0][tid] + b2[tid];
}

// ---------------- Kernel 8: softmax + top2 + renorm + partial sums -------
__global__ __launch_bounds__(256) void softmax_top2_kernel(
    const float* __restrict__ logits, float* __restrict__ probs_out,
    float* __restrict__ top2prob, int* __restrict__ top2idx,
    float* __restrict__ partial)
{
    const int tid = threadIdx.x;
    const int t = blockIdx.x * 256 + tid;

    float l[NE];
    *(float4*)(&l[0]) = *(const float4*)(logits + (size_t)t * NE);
    *(float4*)(&l[4]) = *(const float4*)(logits + (size_t)t * NE + 4);

    float mx = l[0];
#pragma unroll
    for (int e = 1; e < NE; ++e) mx = fmaxf(mx, l[e]);
    float p[NE], sum = 0.f;
#pragma unroll
    for (int e = 0; e < NE; ++e) { p[e] = __expf(l[e] - mx); sum += p[e]; }
    float inv = 1.f / sum;
#pragma unroll
    for (int e = 0; e < NE; ++e) p[e] *= inv;

#pragma unroll
    for (int e = 0; e < NE; ++e) probs_out[(size_t)t * NE + e] = p[e];

    float b1v = -1e30f, b2v = -1e30f;
    int i1 = 0, i2 = 0;
#pragma unroll
    for (int e = 0; e < NE; ++e) {
        float v = l[e];
        if (v > b1v) { b2v = b1v; i2 = i1; b1v = v; i1 = e; }
        else if (v > b2v) { b2v = v; i2 = e; }
    }
    float p1 = 0.f, p2 = 0.f;
#pragma unroll
    for (int e = 0; e < NE; ++e) { if (e == i1) p1 = p[e]; if (e == i2) p2 = p[e]; }
    float s = p1 + p2 + 1e-8f;
    top2prob[2 * t]     = p1 / s;
    top2prob[2 * t + 1] = p2 / s;
    top2idx[2 * t]      = i1;
    top2idx[2 * t + 1]  = i2;

    __shared__ float red[256][NE];
#pragma unroll
    for (int e = 0; e < NE; ++e) red[tid][e] = p[e];
    __syncthreads();
    for (int sdx = 128; sdx > 0; sdx >>= 1) {
        if (tid < sdx) {
#pragma unroll
            for (int e = 0; e < NE; ++e) red[tid][e] += red[tid + sdx][e];
        }
        __syncthreads();
    }
    if (tid < NE) partial[blockIdx.x * NE + tid] = red[0][tid];
}

// ---------------- Kernel 9: sequential capacity scan + slot map + aux ----
__global__ __launch_bounds__(256) void scan_dispatch_kernel(
    const int* __restrict__ top2idx, const float* __restrict__ top2prob,
    const float* __restrict__ partial, int* __restrict__ slot_pos,
    float* __restrict__ slot_val, float* __restrict__ aux_out)
{
    const int tid = threadIdx.x;
    const int ITEMS = NSEL / 256;

    for (int i = tid; i < NTOK * NE; i += 256) { slot_pos[i] = -1; slot_val[i] = 0.f; }

    int cnt[NE];
#pragma unroll
    for (int e = 0; e < NE; ++e) cnt[e] = 0;
    const int base = tid * ITEMS;
    for (int j = 0; j < ITEMS; ++j) {
        int v = top2idx[base + j];
#pragma unroll
        for (int e = 0; e < NE; ++e) cnt[e] += (v == e);
    }

    __shared__ int scnt[256][NE];
    __shared__ int tot[NE];
#pragma unroll
    for (int e = 0; e < NE; ++e) scnt[tid][e] = cnt[e];
    __syncthreads();

    if (tid < NE) {
        int run = 0;
        for (int i = 0; i < 256; ++i) {
            int c = scnt[i][tid];
            scnt[i][tid] = run;
            run += c;
        }
        tot[tid] = run;
    }
    __syncthreads();

    int off[NE];
#pragma unroll
    for (int e = 0; e < NE; ++e) off[e] = scnt[tid][e];
    for (int j = 0; j < ITEMS; ++j) {
        int item = base + j;
        int v = top2idx[item];
        int pos = 0;
#pragma unroll
        for (int e = 0; e < NE; ++e) { if (v == e) { pos = off[e]; off[e]++; } }
        if (pos < CAP) {
            int tok = item >> 1;
            slot_pos[tok * NE + v] = pos;
            slot_val[tok * NE + v] = top2prob[item];
        }
    }

    if (tid == 0) {
        float aux = 0.f;
#pragma unroll
        for (int e = 0; e < NE; ++e) {
            float pp = 0.f;
            for (int b = 0; b < 16; ++b) pp += partial[b * NE + e];
            aux += (pp / (float)NTOK) * ((float)tot[e] / (float)NSEL);
        }
        aux_out[0] = aux * (float)NE;
    }
}

// ---------------- Kernel 10: sparse scatter into zeroed outputs ----------
__global__ __launch_bounds__(256) void scatter_kernel(
    const int* __restrict__ slot_pos, const float* __restrict__ slot_val,
    float* __restrict__ out)
{
    int i = blockIdx.x * 256 + threadIdx.x;   // tok*NE + e, 0..32767
    int sp = slot_pos[i];
    if (sp >= 0) {
        out[(size_t)i * CAP + sp] = 1.0f;
        out[COMB_OFF + (size_t)i * CAP + sp] = slot_val[i];
    }
}

// ---------------- host ---------------------------------------------------
extern "C" void kernel_launch(void* const* d_in, const int* in_sizes, int n_in,
                              void* d_out, int out_size, void* d_ws, size_t ws_size,
                              hipStream_t stream)
{
    const float* x  = (const float*)d_in[0];
    const float* W1 = (const float*)d_in[1];
    const float* b1 = (const float*)d_in[2];
    const float* W2 = (const float*)d_in[3];
    const float* b2 = (const float*)d_in[4];
    float* out = (float*)d_out;

    // Staging in d_out (zeroed by zero_out after consumption; hflag region
    // re-zeroed after fixup since it lives inside the graded dispatch output):
    ushort_t* xp  = (ushort_t*)(out);                   // fp16 panel, 33.5 MB
    ushort_t* wp  = (ushort_t*)(out + 8388608);         // fp16 panel, 33.5 MB
    float*    hflag = out + HFLAG_OFF;                  // MAXFLAG*HD (4 MB)

    // ws layout (float offsets)
    float* ws       = (float*)d_ws;
    float* logits   = ws;
    float* top2prob = ws + 32768;
    int*   top2idx  = (int*)(ws + 40960);
    float* partial  = ws + 49152;
    int*   slot_pos = (int*)(ws + 49280);
    float* slot_val = ws + 82048;
    int*   count    = (int*)(ws + 114816);
    int*   list     = (int*)(ws + 114817);

    convert_x_panel<<<dim3(128, 32), 256, 0, stream>>>(x, xp);
    convert_w1_panel<<<dim3(128, 32), 256, 0, stream>>>(W1, wp);
    init_logits_kernel<<<16, 256, 0, stream>>>(b2, logits);
    gemm16_8phase<<<dim3(16, 16), 512, 0, stream>>>(xp, wp, b1, W2, logits);
    // panels consumed: zero the whole dispatch+combine region now
    // (also zero-inits hflag for stageA's atomicAdd)
    zero_out_kernel<<<8192, 256, 0, stream>>>(out);
    init_count_kernel<<<1, 1, 0, stream>>>(count);
    flag_compact_kernel<<<16, 256, 0, stream>>>(logits, count, list);
    fixup_stageA<<<dim3(64, 4), 256, 0, stream>>>(x, W1, count, list, hflag);
    fixup_stageB<<<MAXFLAG, 256, 0, stream>>>(hflag, b1, W2, b2, count, list, logits);
    // hflag consumed: erase its residue from the dispatch output BEFORE scatter
    zero_hflag_kernel<<<1024, 256, 0, stream>>>(hflag);
    softmax_top2_kernel<<<16, 256, 0, stream>>>(logits, out + PROBS_OFF, top2prob, top2idx, partial);
    scan_dispatch_kernel<<<1, 256, 0, stream>>>(top2idx, top2prob, partial, slot_pos, slot_val, out + AUX_OFF);
    scatter_kernel<<<128, 256, 0, stream>>>(slot_pos, slot_val, out);
}

// Round 5
// 796.641 us; speedup vs baseline: 1.0581x; 1.0181x over previous
//
#include <hip/hip_runtime.h>
#include <cmath>

// Problem constants (fixed by reference setup)
#define NTOK 4096            // B*S = 2*2048
#define HD   4096            // hidden dim
#define NE   8               // experts
#define CAP  1536            // int(B*S*1.5*2/8)
#define NSEL 8192            // NTOK * TOP_K
#define TAU  2.5e-3f         // near-tie gap threshold (fp16 gemm: sigma~4.4e-4 -> 5.7 sigma)
#define MAXFLAG 256
#define GSIZE 32             // flagged tokens per W1 pass in stageA

// d_out layout (float element offsets)
#define COMB_OFF  50331648UL   // NTOK*NE*CAP
#define PROBS_OFF 100663296UL  // 2*NTOK*NE*CAP
#define AUX_OFF   100696064UL  // PROBS_OFF + NTOK*NE
#define HFLAG_OFF 25165824UL   // hflag scratch inside dispatch region (4 MB)
#define PANEL_FLOATS 16777216  // xp+wp = 64 MB at head of d_out

typedef unsigned short ushort_t;
typedef _Float16 half_t;
typedef half_t half8 __attribute__((ext_vector_type(8)));
typedef float floatx16 __attribute__((ext_vector_type(16)));

// Panel format: [group g (32 rows)][kstep ks (32 k)][2048 bytes]; 16B chunk u:
// h=u>>6, l=u&63, r=l&31, oh=l>>5 -> (row r, k=h*16+oh*8+j). Staging: lane l
// sources chunk l / 64+l -> each global_load_lds = one contiguous 1KB burst.

// ---- async 16B global->LDS (gsrc per-lane; lds dest = base+lane*16) ------
__device__ __forceinline__ void async_copy16(const void* g, void* l) {
    __builtin_amdgcn_global_load_lds(
        (const __attribute__((address_space(1))) unsigned int*)g,
        (__attribute__((address_space(3))) unsigned int*)l, 16, 0, 0);
}

// ---------------- Kernel 1: x -> fp16 panels ------------------------------
// grid (128 g, 32 q); block covers rows g*32..+32, k = q*128..+128.
__global__ __launch_bounds__(256) void convert_x_panel(
    const float* __restrict__ x, ushort_t* __restrict__ xp)
{
    __shared__ float xs[32 * 128];      // 16 KB
    const int g = blockIdx.x, q = blockIdx.y, t = threadIdx.x;
#pragma unroll
    for (int i = 0; i < 4; ++i) {
        int idx = i * 256 + t;
        int row = idx >> 5, c4 = (idx & 31) * 4;
        float4 v = *(const float4*)(x + (size_t)(g * 32 + row) * HD + q * 128 + c4);
        *(float4*)(&xs[row * 128 + c4]) = v;
    }
    __syncthreads();
#pragma unroll
    for (int it = 0; it < 2; ++it) {
        int c = it * 256 + t;
        int s = c >> 7, u = c & 127;
        int h = u >> 6, l = u & 63, r = l & 31, oh = l >> 5;
        int kl = s * 32 + h * 16 + oh * 8;
        half8 h8;
#pragma unroll
        for (int j = 0; j < 8; ++j) h8[j] = (half_t)xs[r * 128 + kl + j];
        size_t off = ((size_t)(g * 128 + q * 4 + s)) * 1024 + u * 8;
        *(half8*)(xp + off) = h8;
    }
}

// ---------------- Kernel 2: W1 -> W1^T fp16 panels (transpose) ------------
__global__ __launch_bounds__(256) void convert_w1_panel(
    const float* __restrict__ W1, ushort_t* __restrict__ wp)
{
    __shared__ float ws[32 * 129];      // padded transpose stage
    const int gn = blockIdx.x, q = blockIdx.y, t = threadIdx.x;
#pragma unroll
    for (int i = 0; i < 4; ++i) {
        int idx = i * 256 + t;
        int kr = idx >> 3, c4 = (idx & 7) * 4;
        float4 v = *(const float4*)(W1 + (size_t)(q * 128 + kr) * HD + gn * 32 + c4);
        ws[(c4 + 0) * 129 + kr] = v.x;
        ws[(c4 + 1) * 129 + kr] = v.y;
        ws[(c4 + 2) * 129 + kr] = v.z;
        ws[(c4 + 3) * 129 + kr] = v.w;
    }
    __syncthreads();
#pragma unroll
    for (int it = 0; it < 2; ++it) {
        int c = it * 256 + t;
        int s = c >> 7, u = c & 127;
        int h = u >> 6, l = u & 63, r = l & 31, oh = l >> 5;
        int kl = s * 32 + h * 16 + oh * 8;
        half8 h8;
#pragma unroll
        for (int j = 0; j < 8; ++j) h8[j] = (half_t)ws[r * 129 + kl + j];
        size_t off = ((size_t)(gn * 128 + q * 4 + s)) * 1024 + u * 8;
        *(half8*)(wp + off) = h8;
    }
}

// ---------------- Kernel 3: fused h = relu(x@W1+b1), logits += h@W2 ------
// 256x256 tile, BK=64, 8 waves (2M x 4N), 512 threads, wave tile 128x64 =
// 4x2 of 32x32. LDS: 2 dbuf x 64KB. Stage-early: both half-tiles of kt+1
// issued in phases 0-1; counted waits vmcnt(8) @P1 / vmcnt(4) @P3.
// NEW: 320 MB of d_out zeroing folded into the K-loop as 3 float4 stores/
// thread/kt (kt<54), issued at the START of P0 so in-order vmcnt retirement
// at P1's vmcnt(8) drains exactly [4 needed loads][3 stores] and never a
// fresh load; P3's vmcnt(4) window is unchanged. Stores ack at L2; HBM
// write-back proceeds under MFMA (write BW idle during GEMM).
// Epilogue: logits[row][e] += relu(h)*W2 via transposed LDS tile (no h
// materialization).

#define MFMA8() do { \
    acc[0][0] = __builtin_amdgcn_mfma_f32_32x32x16_f16(ah0, bh0, acc[0][0], 0, 0, 0); \
    acc[0][1] = __builtin_amdgcn_mfma_f32_32x32x16_f16(ah0, bh1, acc[0][1], 0, 0, 0); \
    acc[1][0] = __builtin_amdgcn_mfma_f32_32x32x16_f16(ah1, bh0, acc[1][0], 0, 0, 0); \
    acc[1][1] = __builtin_amdgcn_mfma_f32_32x32x16_f16(ah1, bh1, acc[1][1], 0, 0, 0); \
    acc[2][0] = __builtin_amdgcn_mfma_f32_32x32x16_f16(ah2, bh0, acc[2][0], 0, 0, 0); \
    acc[2][1] = __builtin_amdgcn_mfma_f32_32x32x16_f16(ah2, bh1, acc[2][1], 0, 0, 0); \
    acc[3][0] = __builtin_amdgcn_mfma_f32_32x32x16_f16(ah3, bh0, acc[3][0], 0, 0, 0); \
    acc[3][1] = __builtin_amdgcn_mfma_f32_32x32x16_f16(ah3, bh1, acc[3][1], 0, 0, 0); \
} while (0)

#define LDA(mi, ks) (*(const half8*)&lds[cur * 32768 + ((wm * 4 + (mi)) * 2 + ((ks) >> 1)) * 1024 + ((ks) & 1) * 512 + lsrc])
#define LDB(ni, ks) (*(const half8*)&lds[cur * 32768 + 16384 + ((wn * 2 + (ni)) * 2 + ((ks) >> 1)) * 1024 + ((ks) & 1) * 512 + lsrc])

#define STAGE_A(c, kt, ksu) do { \
    const ushort_t* s_ = srcA + ((size_t)((kt) * 2 + (ksu))) * 1024; \
    ushort_t* d_ = lds + (c) * 32768 + (wave * 2 + (ksu)) * 1024; \
    async_copy16(s_, d_); async_copy16(s_ + 512, d_ + 512); \
} while (0)

#define STAGE_B(c, kt, ksu) do { \
    const ushort_t* s_ = srcB + ((size_t)((kt) * 2 + (ksu))) * 1024; \
    ushort_t* d_ = lds + (c) * 32768 + 16384 + (wave * 2 + (ksu)) * 1024; \
    async_copy16(s_, d_); async_copy16(s_ + 512, d_ + 512); \
} while (0)

#define STAGE_AB(c, kt, ksu) do { STAGE_A(c, kt, ksu); STAGE_B(c, kt, ksu); } while (0)

// 3 zero-stores, issued BEFORE the stage loads in P0 (see vmcnt note above)
#define ZST3(s0) do { \
    if ((s0) < 160)     zbase[(size_t)((s0))     * 131072 + zidx] = zf4; \
    if ((s0) + 1 < 160) zbase[(size_t)((s0) + 1) * 131072 + zidx] = zf4; \
    if ((s0) + 2 < 160) zbase[(size_t)((s0) + 2) * 131072 + zidx] = zf4; \
} while (0)

#define STG_P0 do { ZST3(3 * kt); STAGE_AB(cur ^ 1, kt + 1, 0); } while (0)

#define STAGE_NONE do {} while (0)
#define VM8 asm volatile("s_waitcnt vmcnt(8)" ::: "memory")
#define VM4 asm volatile("s_waitcnt vmcnt(4)" ::: "memory")
#define VM0 asm volatile("s_waitcnt vmcnt(0)" ::: "memory")
#define TW_NONE do {} while (0)

#define PHASE(ks, STG, TW) do { \
    half8 ah0 = LDA(0, ks), ah1 = LDA(1, ks), ah2 = LDA(2, ks), ah3 = LDA(3, ks); \
    half8 bh0 = LDB(0, ks), bh1 = LDB(1, ks); \
    STG; \
    __builtin_amdgcn_s_barrier(); \
    asm volatile("s_waitcnt lgkmcnt(0)" ::: "memory"); \
    __builtin_amdgcn_sched_barrier(0); \
    __builtin_amdgcn_s_setprio(1); \
    MFMA8(); \
    __builtin_amdgcn_s_setprio(0); \
    TW; \
    __builtin_amdgcn_s_barrier(); \
    __builtin_amdgcn_sched_barrier(0); \
} while (0)

__global__ __launch_bounds__(512, 2) void gemm16_8phase(
    const ushort_t* __restrict__ Ap, const ushort_t* __restrict__ Bp,
    const float* __restrict__ bias, const float* __restrict__ W2,
    float* __restrict__ logits_out, float* __restrict__ zout)
{
    __shared__ __attribute__((aligned(16))) ushort_t lds[65536];  // 128 KB

    const int tid  = threadIdx.x;
    const int wave = tid >> 6;
    const int lane = tid & 63;
    const int l31  = lane & 31;
    const int lh   = lane >> 5;
    const int m0 = blockIdx.y * 256;
    const int n0 = blockIdx.x * 256;
    const int wm = wave >> 2;        // 0..1 -> rows wm*128
    const int wn = wave & 3;         // 0..3 -> cols wn*64

    // zero-fold targets: floats [PANEL_FLOATS, 2*NTOK*NE*CAP) = 320 MB
    float4* zbase = (float4*)(zout + PANEL_FLOATS);
    const int zidx = ((blockIdx.y * 16 + blockIdx.x) * 512 + tid);  // 0..131071
    const float4 zf4 = make_float4(0.f, 0.f, 0.f, 0.f);

    floatx16 acc[4][2];
#pragma unroll
    for (int mi = 0; mi < 4; ++mi)
#pragma unroll
        for (int ni = 0; ni < 2; ++ni)
#pragma unroll
            for (int r = 0; r < 16; ++r) acc[mi][ni][r] = 0.f;

    const int lsrc = lane * 8;       // 16 B per lane
    const ushort_t* srcA = Ap + ((size_t)(blockIdx.y * 8 + wave)) * 128 * 1024 + lsrc;
    const ushort_t* srcB = Bp + ((size_t)(blockIdx.x * 8 + wave)) * 128 * 1024 + lsrc;

    // Prologue: stage K-tile 0 fully, keep the last 4 loads in flight.
    STAGE_AB(0, 0, 0);
    STAGE_AB(0, 0, 1);
    VM4;
    __builtin_amdgcn_s_barrier();
    __builtin_amdgcn_sched_barrier(0);

    int cur = 0;
    for (int kt = 0; kt < 63; ++kt) {
        PHASE(0, STG_P0, TW_NONE);
        PHASE(1, STAGE_AB(cur ^ 1, kt + 1, 1), VM8);
        PHASE(2, STAGE_NONE, TW_NONE);
        PHASE(3, STAGE_NONE, VM4);
        cur ^= 1;
    }
    // Peeled last K-tile (kt=63): no prefetch; single drain before H1 phases.
    PHASE(0, STAGE_NONE, TW_NONE);
    PHASE(1, STAGE_NONE, VM0);
    PHASE(2, STAGE_NONE, TW_NONE);
    PHASE(3, STAGE_NONE, TW_NONE);

    // ---- fused logits epilogue (reuses the 128 KB LDS; all loads drained,
    // final phase barrier passed => safe to overwrite) --------------------
    // Ls_T[col 0..255][row 0..63] pad 65 (floats 0..16639)
    // W2s[256][8]                       (floats 16640..18687)
    // Rs[wave][64][8] pad 9             (floats 18688..23295)
    float* Lf  = (float*)lds;
    float* W2s = Lf + 16640;
    float* Rs  = Lf + 18688;

    // cache W2 slice for this block's 256 columns: 2048 floats, contiguous
    ((float4*)W2s)[tid] = ((const float4*)(W2 + (size_t)n0 * NE))[tid];

    const int ncol = n0 + wn * 64 + l31;
    const float b1v0 = bias[ncol];
    const float b1v1 = bias[ncol + 32];
    const int lcol = wn * 64 + l31;
    const int lrow_base = wm * 32;

    for (int mi = 0; mi < 4; ++mi) {
        __syncthreads();   // prev mi consumed (and W2s visible on first iter)
#pragma unroll
        for (int r = 0; r < 16; ++r) {
            int lr = lrow_base + (r & 3) + 8 * (r >> 2) + 4 * lh;
            float v0 = acc[mi][0][r] + b1v0;
            float v1 = acc[mi][1][r] + b1v1;
            Lf[(lcol)      * 65 + lr] = v0 > 0.f ? v0 : 0.f;
            Lf[(lcol + 32) * 65 + lr] = v1 > 0.f ? v1 : 0.f;
        }
        __syncthreads();
        // wave w reduces cols w*32..+31 over all 64 rows (lane = row)
        float le[NE];
#pragma unroll
        for (int e = 0; e < NE; ++e) le[e] = 0.f;
        for (int c = 0; c < 32; ++c) {
            int col = wave * 32 + c;
            float hv = Lf[col * 65 + lane];
            float4 wa = *(const float4*)&W2s[col * 8];
            float4 wb = *(const float4*)&W2s[col * 8 + 4];
            le[0] += hv * wa.x; le[1] += hv * wa.y; le[2] += hv * wa.z; le[3] += hv * wa.w;
            le[4] += hv * wb.x; le[5] += hv * wb.y; le[6] += hv * wb.z; le[7] += hv * wb.w;
        }
#pragma unroll
        for (int e = 0; e < NE; ++e) Rs[(wave * 64 + lane) * 9 + e] = le[e];
        __syncthreads();
        {
            int rr = tid >> 3, e = tid & 7;      // 512 threads = 64 rows x 8 e
            float s = 0.f;
#pragma unroll
            for (int w = 0; w < 8; ++w) s += Rs[(w * 64 + rr) * 9 + e];
            int row_g = m0 + (rr >> 5) * 128 + mi * 32 + (rr & 31);
            atomicAdd(&logits_out[(size_t)row_g * NE + e], s);
        }
    }
}

// ---------------- Kernel 4: logits = b2 (init for gemm atomics) ----------
__global__ __launch_bounds__(256) void init_logits_kernel(
    const float* __restrict__ b2, float* __restrict__ logits)
{
    int t = blockIdx.x * 256 + threadIdx.x;   // 16 blocks x 256 = NTOK
    float4 v0 = *(const float4*)b2;
    float4 v1 = *(const float4*)(b2 + 4);
    float4* dst = (float4*)(logits + (size_t)t * NE);
    dst[0] = v0; dst[1] = v1;
}

// ---------------- Kernel 5: zero the panel region (64 MB at d_out head) --
__global__ __launch_bounds__(256) void zero_panels_kernel(float* __restrict__ out)
{
    const int TOTALQ = PANEL_FLOATS / 4;   // 4194304 float4
    int stride = gridDim.x * 256;
    float4 z = make_float4(0.f, 0.f, 0.f, 0.f);
    for (int q = blockIdx.x * 256 + threadIdx.x; q < TOTALQ; q += stride)
        ((float4*)out)[q] = z;
}

// ---------------- Kernel 5b: init count ----------------------------------
__global__ void init_count_kernel(int* __restrict__ count) { *count = 0; }

// ---------------- Kernel 5c: re-zero hflag residue (inside dispatch out) --
__global__ __launch_bounds__(256) void zero_hflag_kernel(float* __restrict__ hflag)
{
    int i = blockIdx.x * 256 + threadIdx.x;   // 1024 blocks: 262144 float4 = 4 MB
    ((float4*)hflag)[i] = make_float4(0.f, 0.f, 0.f, 0.f);
}

// ---------------- Kernel 6: flag near-ties, compact list -----------------
__global__ __launch_bounds__(256) void flag_compact_kernel(
    const float* __restrict__ logits, int* __restrict__ count, int* __restrict__ list)
{
    int t = blockIdx.x * 256 + threadIdx.x;
    float l[NE];
    *(float4*)(&l[0]) = *(const float4*)(logits + (size_t)t * NE);
    *(float4*)(&l[4]) = *(const float4*)(logits + (size_t)t * NE + 4);
    float a = -1e30f, b = -1e30f, c = -1e30f;
#pragma unroll
    for (int e = 0; e < NE; ++e) {
        float v = l[e];
        if (v > a) { c = b; b = a; a = v; }
        else if (v > b) { c = b; b = v; }
        else if (v > c) { c = v; }
    }
    if (b - c < TAU) {
        int p = atomicAdd(count, 1);
        if (p < MAXFLAG) list[p] = t;
    }
}

// ---------------- Kernel 7a: batched exact pre-activation h for flagged --
// grid (64 f-chunks, 4 k-splits); one W1 pass per 32 flagged tokens.
__global__ __launch_bounds__(256) void fixup_stageA(
    const float* __restrict__ x, const float* __restrict__ W1,
    const int* __restrict__ count_p, const int* __restrict__ list,
    float* __restrict__ hflag)
{
    __shared__ float xs[GSIZE][256];          // 32 KB
    __shared__ float red[4][GSIZE][64];       // 32 KB
    const int tid = threadIdx.x;
    const int fl  = tid & 63;
    const int kg  = tid >> 6;
    const int f   = blockIdx.x * 64 + fl;
    const int kbase = blockIdx.y * 1024;
    int count = *count_p;
    if (count > MAXFLAG) count = MAXFLAG;

    for (int g = 0; g * GSIZE < count; ++g) {
        const int gbase = g * GSIZE;
        int ntok = count - gbase; if (ntok > GSIZE) ntok = GSIZE;

        float acc[GSIZE];
#pragma unroll
        for (int t = 0; t < GSIZE; ++t) acc[t] = 0.f;

        for (int kb = 0; kb < 1024; kb += 256) {
            __syncthreads();
            for (int i = tid; i < ntok * 256; i += 256) {
                int t = i >> 8, kk = i & 255;
                xs[t][kk] = x[(size_t)list[gbase + t] * HD + kbase + kb + kk];
            }
            __syncthreads();
            for (int j = 0; j < 64; ++j) {
                int kk = kg * 64 + j;
                float w = W1[(size_t)(kbase + kb + kk) * HD + f];
#pragma unroll
                for (int t = 0; t < GSIZE; ++t) acc[t] += xs[t][kk] * w;
            }
        }
        __syncthreads();
#pragma unroll
        for (int t = 0; t < GSIZE; ++t) red[kg][t][fl] = acc[t];
        __syncthreads();
        if (kg == 0) {
            for (int t = 0; t < ntok; ++t) {
                float v = red[0][t][fl] + red[1][t][fl] + red[2][t][fl] + red[3][t][fl];
                atomicAdd(&hflag[(size_t)(gbase + t) * HD + f], v);
            }
        }
        __syncthreads();
    }
}

// ---------------- Kernel 7b: exact logits for flagged tokens -------------
__global__ __launch_bounds__(256) void fixup_stageB(
    const float* __restrict__ hflag, const float* __restrict__ b1,
    const float* __restrict__ W2, const float* __restrict__ b2,
    const int* __restrict__ count_p, const int* __restrict__ list,
    float* __restrict__ logits)
{
    int count = *count_p;
    if (count > MAXFLAG) count = MAXFLAG;
    const int b = blockIdx.x;
    if (b >= count) return;
    const int tok = list[b];
    const int tid = threadIdx.x;

    float acc[NE];
#pragma unroll
    for (int e = 0; e < NE; ++e) acc[e] = 0.f;
    for (int f = tid; f < HD; f += 256) {
        float hv = hflag[(size_t)b * HD + f] + b1[f];
        hv = hv > 0.f ? hv : 0.f;
        float4 w0 = *(const float4*)(W2 + (size_t)f * NE);
        float4 w1 = *(const float4*)(W2 + (size_t)f * NE + 4);
        acc[0] += hv * w0.x; acc[1] += hv * w0.y; acc[2] += hv * w0.z; acc[3] += hv * w0.w;
        acc[4] += hv * w1.x; acc[5] += hv * w1.y; acc[6] += hv * w1.z; acc[7] += hv * w1.w;
    }
    __shared__ float red[256][NE];
#pragma unroll
    for (int e = 0; e < NE; ++e) red[tid][e] = acc[e];
    __syncthreads();
    for (int s = 128; s > 0; s >>= 1) {
        if (tid < s) {
#pragma unroll
            for (int e = 0; e < NE; ++e) red[tid][e] += red[tid + s][e];
        }
        __syncthreads();
    }
    if (tid < NE) logits[(size_t)tok * NE + tid] = red[0][tid] + b2[tid];
}

// ---------------- Kernel 8: softmax + top2 + renorm + partial sums -------
__global__ __launch_bounds__(256) void softmax_top2_kernel(
    const float* __restrict__ logits, float* __restrict__ probs_out,
    float* __restrict__ top2prob, int* __restrict__ top2idx,
    float* __restrict__ partial)
{
    const int tid = threadIdx.x;
    const int t = blockIdx.x * 256 + tid;

    float l[NE];
    *(float4*)(&l[0]) = *(const float4*)(logits + (size_t)t * NE);
    *(float4*)(&l[4]) = *(const float4*)(logits + (size_t)t * NE + 4);

    float mx = l[0];
#pragma unroll
    for (int e = 1; e < NE; ++e) mx = fmaxf(mx, l[e]);
    float p[NE], sum = 0.f;
#pragma unroll
    for (int e = 0; e < NE; ++e) { p[e] = __expf(l[e] - mx); sum += p[e]; }
    float inv = 1.f / sum;
#pragma unroll
    for (int e = 0; e < NE; ++e) p[e] *= inv;

#pragma unroll
    for (int e = 0; e < NE; ++e) probs_out[(size_t)t * NE + e] = p[e];

    float b1v = -1e30f, b2v = -1e30f;
    int i1 = 0, i2 = 0;
#pragma unroll
    for (int e = 0; e < NE; ++e) {
        float v = l[e];
        if (v > b1v) { b2v = b1v; i2 = i1; b1v = v; i1 = e; }
        else if (v > b2v) { b2v = v; i2 = e; }
    }
    float p1 = 0.f, p2 = 0.f;
#pragma unroll
    for (int e = 0; e < NE; ++e) { if (e == i1) p1 = p[e]; if (e == i2) p2 = p[e]; }
    float s = p1 + p2 + 1e-8f;
    top2prob[2 * t]     = p1 / s;
    top2prob[2 * t + 1] = p2 / s;
    top2idx[2 * t]      = i1;
    top2idx[2 * t + 1]  = i2;

    __shared__ float red[256][NE];
#pragma unroll
    for (int e = 0; e < NE; ++e) red[tid][e] = p[e];
    __syncthreads();
    for (int sdx = 128; sdx > 0; sdx >>= 1) {
        if (tid < sdx) {
#pragma unroll
            for (int e = 0; e < NE; ++e) red[tid][e] += red[tid + sdx][e];
        }
        __syncthreads();
    }
    if (tid < NE) partial[blockIdx.x * NE + tid] = red[0][tid];
}

// ---------------- Kernel 9: sequential capacity scan + slot map + aux ----
__global__ __launch_bounds__(256) void scan_dispatch_kernel(
    const int* __restrict__ top2idx, const float* __restrict__ top2prob,
    const float* __restrict__ partial, int* __restrict__ slot_pos,
    float* __restrict__ slot_val, float* __restrict__ aux_out)
{
    const int tid = threadIdx.x;
    const int ITEMS = NSEL / 256;

    for (int i = tid; i < NTOK * NE; i += 256) { slot_pos[i] = -1; slot_val[i] = 0.f; }

    int cnt[NE];
#pragma unroll
    for (int e = 0; e < NE; ++e) cnt[e] = 0;
    const int base = tid * ITEMS;
    for (int j = 0; j < ITEMS; ++j) {
        int v = top2idx[base + j];
#pragma unroll
        for (int e = 0; e < NE; ++e) cnt[e] += (v == e);
    }

    __shared__ int scnt[256][NE];
    __shared__ int tot[NE];
#pragma unroll
    for (int e = 0; e < NE; ++e) scnt[tid][e] = cnt[e];
    __syncthreads();

    if (tid < NE) {
        int run = 0;
        for (int i = 0; i < 256; ++i) {
            int c = scnt[i][tid];
            scnt[i][tid] = run;
            run += c;
        }
        tot[tid] = run;
    }
    __syncthreads();

    int off[NE];
#pragma unroll
    for (int e = 0; e < NE; ++e) off[e] = scnt[tid][e];
    for (int j = 0; j < ITEMS; ++j) {
        int item = base + j;
        int v = top2idx[item];
        int pos = 0;
#pragma unroll
        for (int e = 0; e < NE; ++e) { if (v == e) { pos = off[e]; off[e]++; } }
        if (pos < CAP) {
            int tok = item >> 1;
            slot_pos[tok * NE + v] = pos;
            slot_val[tok * NE + v] = top2prob[item];
        }
    }

    if (tid == 0) {
        float aux = 0.f;
#pragma unroll
        for (int e = 0; e < NE; ++e) {
            float pp = 0.f;
            for (int b = 0; b < 16; ++b) pp += partial[b * NE + e];
            aux += (pp / (float)NTOK) * ((float)tot[e] / (float)NSEL);
        }
        aux_out[0] = aux * (float)NE;
    }
}

// ---------------- Kernel 10: sparse scatter into zeroed outputs ----------
__global__ __launch_bounds__(256) void scatter_kernel(
    const int* __restrict__ slot_pos, const float* __restrict__ slot_val,
    float* __restrict__ out)
{
    int i = blockIdx.x * 256 + threadIdx.x;   // tok*NE + e, 0..32767
    int sp = slot_pos[i];
    if (sp >= 0) {
        out[(size_t)i * CAP + sp] = 1.0f;
        out[COMB_OFF + (size_t)i * CAP + sp] = slot_val[i];
    }
}

// ---------------- host ---------------------------------------------------
extern "C" void kernel_launch(void* const* d_in, const int* in_sizes, int n_in,
                              void* d_out, int out_size, void* d_ws, size_t ws_size,
                              hipStream_t stream)
{
    const float* x  = (const float*)d_in[0];
    const float* W1 = (const float*)d_in[1];
    const float* b1 = (const float*)d_in[2];
    const float* W2 = (const float*)d_in[3];
    const float* b2 = (const float*)d_in[4];
    float* out = (float*)d_out;

    // Staging in d_out (panel region zeroed by zero_panels after gemm; the
    // rest of dispatch+combine (320 MB) zeroed BY the gemm's folded stores,
    // incl. the hflag zone consumed by fixup then re-zeroed pre-scatter):
    ushort_t* xp  = (ushort_t*)(out);                   // fp16 panel, 32 MB
    ushort_t* wp  = (ushort_t*)(out + 8388608);         // fp16 panel, 32 MB
    float*    hflag = out + HFLAG_OFF;                  // MAXFLAG*HD (4 MB)

    // ws layout (float offsets)
    float* ws       = (float*)d_ws;
    float* logits   = ws;
    float* top2prob = ws + 32768;
    int*   top2idx  = (int*)(ws + 40960);
    float* partial  = ws + 49152;
    int*   slot_pos = (int*)(ws + 49280);
    float* slot_val = ws + 82048;
    int*   count    = (int*)(ws + 114816);
    int*   list     = (int*)(ws + 114817);

    convert_x_panel<<<dim3(128, 32), 256, 0, stream>>>(x, xp);
    convert_w1_panel<<<dim3(128, 32), 256, 0, stream>>>(W1, wp);
    init_logits_kernel<<<16, 256, 0, stream>>>(b2, logits);
    gemm16_8phase<<<dim3(16, 16), 512, 0, stream>>>(xp, wp, b1, W2, logits, out);
    // panels consumed by gemm: zero the first 64 MB now (rest already zeroed
    // by the gemm's folded stores)
    zero_panels_kernel<<<4096, 256, 0, stream>>>(out);
    init_count_kernel<<<1, 1, 0, stream>>>(count);
    flag_compact_kernel<<<16, 256, 0, stream>>>(logits, count, list);
    fixup_stageA<<<dim3(64, 4), 256, 0, stream>>>(x, W1, count, list, hflag);
    fixup_stageB<<<MAXFLAG, 256, 0, stream>>>(hflag, b1, W2, b2, count, list, logits);
    // hflag consumed: erase its residue from the dispatch output BEFORE scatter
    zero_hflag_kernel<<<1024, 256, 0, stream>>>(hflag);
    softmax_top2_kernel<<<16, 256, 0, stream>>>(logits, out + PROBS_OFF, top2prob, top2idx, partial);
    scan_dispatch_kernel<<<1, 256, 0, stream>>>(top2idx, top2prob, partial, slot_pos, slot_val, out + AUX_OFF);
    scatter_kernel<<<128, 256, 0, stream>>>(slot_pos, slot_val, out);
}

// Round 6
// 788.498 us; speedup vs baseline: 1.0690x; 1.0103x over previous
//
#include <hip/hip_runtime.h>
#include <cmath>

// Problem constants (fixed by reference setup)
#define NTOK 4096            // B*S = 2*2048
#define HD   4096            // hidden dim
#define NE   8               // experts
#define CAP  1536            // int(B*S*1.5*2/8)
#define NSEL 8192            // NTOK * TOP_K
#define TAU  2.5e-3f         // near-tie gap threshold (fp16 gemm: sigma~4.4e-4 -> 5.7 sigma)
#define MAXFLAG 256
#define GSIZE 32             // flagged tokens per W1 pass in stageA

// d_out layout (float element offsets)
#define COMB_OFF  50331648UL   // NTOK*NE*CAP
#define PROBS_OFF 100663296UL  // 2*NTOK*NE*CAP
#define AUX_OFF   100696064UL  // PROBS_OFF + NTOK*NE
#define HFLAG_OFF 25165824UL   // hflag scratch inside dispatch region (4 MB)
#define PANEL_FLOATS 16777216  // xp+wp = 64 MB at head of d_out

typedef unsigned short ushort_t;
typedef _Float16 half_t;
typedef half_t half8 __attribute__((ext_vector_type(8)));
typedef float floatx16 __attribute__((ext_vector_type(16)));

// Panel format: [group g (32 rows)][kstep ks (32 k)][2048 bytes]; 16B chunk u:
// h=u>>6, l=u&63, r=l&31, oh=l>>5 -> (row r, k=h*16+oh*8+j). Staging: lane l
// sources chunk l / 64+l -> each global_load_lds = one contiguous 1KB burst.

// ---- async 16B global->LDS (gsrc per-lane; lds dest = base+lane*16) ------
__device__ __forceinline__ void async_copy16(const void* g, void* l) {
    __builtin_amdgcn_global_load_lds(
        (const __attribute__((address_space(1))) unsigned int*)g,
        (__attribute__((address_space(3))) unsigned int*)l, 16, 0, 0);
}

// ---------------- Kernel 1: x -> fp16 panels (+ logits=b2 init) -----------
// grid (128 g, 32 q); block covers rows g*32..+32, k = q*128..+128.
__global__ __launch_bounds__(256) void convert_x_panel(
    const float* __restrict__ x, ushort_t* __restrict__ xp,
    const float* __restrict__ b2, float* __restrict__ logits)
{
    __shared__ float xs[32 * 128];      // 16 KB
    const int g = blockIdx.x, q = blockIdx.y, t = threadIdx.x;
#pragma unroll
    for (int i = 0; i < 4; ++i) {
        int idx = i * 256 + t;
        int row = idx >> 5, c4 = (idx & 31) * 4;
        float4 v = *(const float4*)(x + (size_t)(g * 32 + row) * HD + q * 128 + c4);
        *(float4*)(&xs[row * 128 + c4]) = v;
    }
    __syncthreads();
#pragma unroll
    for (int it = 0; it < 2; ++it) {
        int c = it * 256 + t;
        int s = c >> 7, u = c & 127;
        int h = u >> 6, l = u & 63, r = l & 31, oh = l >> 5;
        int kl = s * 32 + h * 16 + oh * 8;
        half8 h8;
#pragma unroll
        for (int j = 0; j < 8; ++j) h8[j] = (half_t)xs[r * 128 + kl + j];
        size_t off = ((size_t)(g * 128 + q * 4 + s)) * 1024 + u * 8;
        *(half8*)(xp + off) = h8;
    }
    // folded init: logits[t][e] = b2[e] (16 blocks cover NTOK tokens)
    if (q == 0 && g < 16) {
        int tok = g * 256 + t;
        float4 v0 = *(const float4*)b2;
        float4 v1 = *(const float4*)(b2 + 4);
        float4* dst = (float4*)(logits + (size_t)tok * NE);
        dst[0] = v0; dst[1] = v1;
    }
}

// ---------------- Kernel 2: W1 -> W1^T fp16 panels (transpose) ------------
__global__ __launch_bounds__(256) void convert_w1_panel(
    const float* __restrict__ W1, ushort_t* __restrict__ wp)
{
    __shared__ float ws[32 * 129];      // padded transpose stage
    const int gn = blockIdx.x, q = blockIdx.y, t = threadIdx.x;
#pragma unroll
    for (int i = 0; i < 4; ++i) {
        int idx = i * 256 + t;
        int kr = idx >> 3, c4 = (idx & 7) * 4;
        float4 v = *(const float4*)(W1 + (size_t)(q * 128 + kr) * HD + gn * 32 + c4);
        ws[(c4 + 0) * 129 + kr] = v.x;
        ws[(c4 + 1) * 129 + kr] = v.y;
        ws[(c4 + 2) * 129 + kr] = v.z;
        ws[(c4 + 3) * 129 + kr] = v.w;
    }
    __syncthreads();
#pragma unroll
    for (int it = 0; it < 2; ++it) {
        int c = it * 256 + t;
        int s = c >> 7, u = c & 127;
        int h = u >> 6, l = u & 63, r = l & 31, oh = l >> 5;
        int kl = s * 32 + h * 16 + oh * 8;
        half8 h8;
#pragma unroll
        for (int j = 0; j < 8; ++j) h8[j] = (half_t)ws[r * 129 + kl + j];
        size_t off = ((size_t)(gn * 128 + q * 4 + s)) * 1024 + u * 8;
        *(half8*)(wp + off) = h8;
    }
}

// ---------------- Kernel 3: fused h = relu(x@W1+b1), logits += h@W2 ------
// 256x256 tile, BK=64, 8 waves (2M x 4N), 512 threads, wave tile 128x64 =
// 4x2 of 32x32. LDS: 2 dbuf x 64KB. NEW: 2 phases per K-tile, 16 MFMA per
// phase (halved barrier overhead vs 4-phase). vmcnt ledger (valid for ANY
// issue order inside a phase; stores retire early harmlessly): entering kt
// P0 queue=[kt.ksu1 x4]; P0 reads ks0/ks1, issues [3 zstores][kt+1.ksu0 x4],
// VM4 retires stores+kt.ksu1; P1 reads ks2/ks3, issues [kt+1.ksu1 x4], VM4
// retires kt+1.ksu0 (1 full phase of slack, panels L2/L3-warm). Peeled kt63
// drains VM0 once. 320 MB zero-fold (3 float4/thread/kt, kt<54) unchanged.
// Raw s_barrier + lgkmcnt(0) + sched_barrier(0) per rule 18; setprio around
// the MFMA cluster. Epilogue: logits += relu(h)*W2 via transposed LDS tile.

#define MFMA8N(A0, A1, A2, A3, B0, B1) do { \
    acc[0][0] = __builtin_amdgcn_mfma_f32_32x32x16_f16(A0, B0, acc[0][0], 0, 0, 0); \
    acc[0][1] = __builtin_amdgcn_mfma_f32_32x32x16_f16(A0, B1, acc[0][1], 0, 0, 0); \
    acc[1][0] = __builtin_amdgcn_mfma_f32_32x32x16_f16(A1, B0, acc[1][0], 0, 0, 0); \
    acc[1][1] = __builtin_amdgcn_mfma_f32_32x32x16_f16(A1, B1, acc[1][1], 0, 0, 0); \
    acc[2][0] = __builtin_amdgcn_mfma_f32_32x32x16_f16(A2, B0, acc[2][0], 0, 0, 0); \
    acc[2][1] = __builtin_amdgcn_mfma_f32_32x32x16_f16(A2, B1, acc[2][1], 0, 0, 0); \
    acc[3][0] = __builtin_amdgcn_mfma_f32_32x32x16_f16(A3, B0, acc[3][0], 0, 0, 0); \
    acc[3][1] = __builtin_amdgcn_mfma_f32_32x32x16_f16(A3, B1, acc[3][1], 0, 0, 0); \
} while (0)

#define LDA(mi, ks) (*(const half8*)&lds[cur * 32768 + ((wm * 4 + (mi)) * 2 + ((ks) >> 1)) * 1024 + ((ks) & 1) * 512 + lsrc])
#define LDB(ni, ks) (*(const half8*)&lds[cur * 32768 + 16384 + ((wn * 2 + (ni)) * 2 + ((ks) >> 1)) * 1024 + ((ks) & 1) * 512 + lsrc])

#define STAGE_A(c, kt, ksu) do { \
    const ushort_t* s_ = srcA + ((size_t)((kt) * 2 + (ksu))) * 1024; \
    ushort_t* d_ = lds + (c) * 32768 + (wave * 2 + (ksu)) * 1024; \
    async_copy16(s_, d_); async_copy16(s_ + 512, d_ + 512); \
} while (0)

#define STAGE_B(c, kt, ksu) do { \
    const ushort_t* s_ = srcB + ((size_t)((kt) * 2 + (ksu))) * 1024; \
    ushort_t* d_ = lds + (c) * 32768 + 16384 + (wave * 2 + (ksu)) * 1024; \
    async_copy16(s_, d_); async_copy16(s_ + 512, d_ + 512); \
} while (0)

#define STAGE_AB(c, kt, ksu) do { STAGE_A(c, kt, ksu); STAGE_B(c, kt, ksu); } while (0)

// 3 zero-stores, issued with P0's stage (any order safe per ledger above)
#define ZST3(s0) do { \
    if ((s0) < 160)     zbase[(size_t)((s0))     * 131072 + zidx] = zf4; \
    if ((s0) + 1 < 160) zbase[(size_t)((s0) + 1) * 131072 + zidx] = zf4; \
    if ((s0) + 2 < 160) zbase[(size_t)((s0) + 2) * 131072 + zidx] = zf4; \
} while (0)

#define STG_P0 do { ZST3(3 * kt); STAGE_AB(cur ^ 1, kt + 1, 0); } while (0)

#define STAGE_NONE do {} while (0)
#define VM4 asm volatile("s_waitcnt vmcnt(4)" ::: "memory")
#define VM0 asm volatile("s_waitcnt vmcnt(0)" ::: "memory")
#define TW_NONE do {} while (0)

#define PHASE2(ksA, ksB, STG, TW) do { \
    half8 pa0 = LDA(0, ksA), pa1 = LDA(1, ksA), pa2 = LDA(2, ksA), pa3 = LDA(3, ksA); \
    half8 pb0 = LDB(0, ksA), pb1 = LDB(1, ksA); \
    half8 qa0 = LDA(0, ksB), qa1 = LDA(1, ksB), qa2 = LDA(2, ksB), qa3 = LDA(3, ksB); \
    half8 qb0 = LDB(0, ksB), qb1 = LDB(1, ksB); \
    STG; \
    __builtin_amdgcn_s_barrier(); \
    asm volatile("s_waitcnt lgkmcnt(0)" ::: "memory"); \
    __builtin_amdgcn_sched_barrier(0); \
    __builtin_amdgcn_s_setprio(1); \
    MFMA8N(pa0, pa1, pa2, pa3, pb0, pb1); \
    MFMA8N(qa0, qa1, qa2, qa3, qb0, qb1); \
    __builtin_amdgcn_s_setprio(0); \
    TW; \
    __builtin_amdgcn_s_barrier(); \
    __builtin_amdgcn_sched_barrier(0); \
} while (0)

__global__ __launch_bounds__(512, 2) void gemm16_8phase(
    const ushort_t* __restrict__ Ap, const ushort_t* __restrict__ Bp,
    const float* __restrict__ bias, const float* __restrict__ W2,
    float* __restrict__ logits_out, float* __restrict__ zout,
    int* __restrict__ count_p)
{
    __shared__ __attribute__((aligned(16))) ushort_t lds[65536];  // 128 KB

    const int tid  = threadIdx.x;
    const int wave = tid >> 6;
    const int lane = tid & 63;
    const int l31  = lane & 31;
    const int lh   = lane >> 5;
    const int m0 = blockIdx.y * 256;
    const int n0 = blockIdx.x * 256;
    const int wm = wave >> 2;        // 0..1 -> rows wm*128
    const int wn = wave & 3;         // 0..3 -> cols wn*64

    // folded init: count=0 (done by one block; complete before flag stage)
    if (blockIdx.x == 0 && blockIdx.y == 0 && tid == 0) *count_p = 0;

    // zero-fold targets: floats [PANEL_FLOATS, 2*NTOK*NE*CAP) = 320 MB
    float4* zbase = (float4*)(zout + PANEL_FLOATS);
    const int zidx = ((blockIdx.y * 16 + blockIdx.x) * 512 + tid);  // 0..131071
    const float4 zf4 = make_float4(0.f, 0.f, 0.f, 0.f);

    floatx16 acc[4][2];
#pragma unroll
    for (int mi = 0; mi < 4; ++mi)
#pragma unroll
        for (int ni = 0; ni < 2; ++ni)
#pragma unroll
            for (int r = 0; r < 16; ++r) acc[mi][ni][r] = 0.f;

    const int lsrc = lane * 8;       // 16 B per lane
    const ushort_t* srcA = Ap + ((size_t)(blockIdx.y * 8 + wave)) * 128 * 1024 + lsrc;
    const ushort_t* srcB = Bp + ((size_t)(blockIdx.x * 8 + wave)) * 128 * 1024 + lsrc;

    // Prologue: stage K-tile 0 fully; VM4 retires (count-store+)ksu0, keeps
    // ksu1's 4 loads in flight -> entering kt0 P0 queue = [ksu1 x4].
    STAGE_AB(0, 0, 0);
    STAGE_AB(0, 0, 1);
    VM4;
    __builtin_amdgcn_s_barrier();
    __builtin_amdgcn_sched_barrier(0);

    int cur = 0;
    for (int kt = 0; kt < 63; ++kt) {
        PHASE2(0, 1, STG_P0, VM4);
        PHASE2(2, 3, STAGE_AB(cur ^ 1, kt + 1, 1), VM4);
        cur ^= 1;
    }
    // Peeled last K-tile (kt=63): no prefetch; single drain before ksu1 read.
    PHASE2(0, 1, STAGE_NONE, VM0);
    PHASE2(2, 3, STAGE_NONE, TW_NONE);

    // ---- fused logits epilogue (reuses the 128 KB LDS; all loads drained,
    // final phase barrier passed => safe to overwrite) --------------------
    // Ls_T[col 0..255][row 0..63] pad 65 (floats 0..16639)
    // W2s[256][8]                       (floats 16640..18687)
    // Rs[wave][64][8] pad 9             (floats 18688..23295)
    float* Lf  = (float*)lds;
    float* W2s = Lf + 16640;
    float* Rs  = Lf + 18688;

    // cache W2 slice for this block's 256 columns: 2048 floats, contiguous
    ((float4*)W2s)[tid] = ((const float4*)(W2 + (size_t)n0 * NE))[tid];

    const int ncol = n0 + wn * 64 + l31;
    const float b1v0 = bias[ncol];
    const float b1v1 = bias[ncol + 32];
    const int lcol = wn * 64 + l31;
    const int lrow_base = wm * 32;

    for (int mi = 0; mi < 4; ++mi) {
        __syncthreads();   // prev mi consumed (and W2s visible on first iter)
#pragma unroll
        for (int r = 0; r < 16; ++r) {
            int lr = lrow_base + (r & 3) + 8 * (r >> 2) + 4 * lh;
            float v0 = acc[mi][0][r] + b1v0;
            float v1 = acc[mi][1][r] + b1v1;
            Lf[(lcol)      * 65 + lr] = v0 > 0.f ? v0 : 0.f;
            Lf[(lcol + 32) * 65 + lr] = v1 > 0.f ? v1 : 0.f;
        }
        __syncthreads();
        // wave w reduces cols w*32..+31 over all 64 rows (lane = row)
        float le[NE];
#pragma unroll
        for (int e = 0; e < NE; ++e) le[e] = 0.f;
        for (int c = 0; c < 32; ++c) {
            int col = wave * 32 + c;
            float hv = Lf[col * 65 + lane];
            float4 wa = *(const float4*)&W2s[col * 8];
            float4 wb = *(const float4*)&W2s[col * 8 + 4];
            le[0] += hv * wa.x; le[1] += hv * wa.y; le[2] += hv * wa.z; le[3] += hv * wa.w;
            le[4] += hv * wb.x; le[5] += hv * wb.y; le[6] += hv * wb.z; le[7] += hv * wb.w;
        }
#pragma unroll
        for (int e = 0; e < NE; ++e) Rs[(wave * 64 + lane) * 9 + e] = le[e];
        __syncthreads();
        {
            int rr = tid >> 3, e = tid & 7;      // 512 threads = 64 rows x 8 e
            float s = 0.f;
#pragma unroll
            for (int w = 0; w < 8; ++w) s += Rs[(w * 64 + rr) * 9 + e];
            int row_g = m0 + (rr >> 5) * 128 + mi * 32 + (rr & 31);
            atomicAdd(&logits_out[(size_t)row_g * NE + e], s);
        }
    }
}

// ---------------- Kernel 4: zero panels + flag near-ties + slot init -----
// 4096 blocks: all zero the 64 MB panel region; blocks 0-15 additionally
// run flag_compact (count was zeroed by the gemm); blocks 16-143 init the
// slot_pos/slot_val arrays (removed from the serial scan kernel).
__global__ __launch_bounds__(256) void zero_panels_kernel(
    float* __restrict__ out, const float* __restrict__ logits,
    int* __restrict__ count, int* __restrict__ list,
    int* __restrict__ slot_pos, float* __restrict__ slot_val)
{
    const int TOTALQ = PANEL_FLOATS / 4;   // 4194304 float4
    int stride = gridDim.x * 256;
    float4 z = make_float4(0.f, 0.f, 0.f, 0.f);
    for (int q = blockIdx.x * 256 + threadIdx.x; q < TOTALQ; q += stride)
        ((float4*)out)[q] = z;

    if (blockIdx.x < 16) {
        int t = blockIdx.x * 256 + threadIdx.x;
        float l[NE];
        *(float4*)(&l[0]) = *(const float4*)(logits + (size_t)t * NE);
        *(float4*)(&l[4]) = *(const float4*)(logits + (size_t)t * NE + 4);
        float a = -1e30f, b = -1e30f, c = -1e30f;
#pragma unroll
        for (int e = 0; e < NE; ++e) {
            float v = l[e];
            if (v > a) { c = b; b = a; a = v; }
            else if (v > b) { c = b; b = v; }
            else if (v > c) { c = v; }
        }
        if (b - c < TAU) {
            int p = atomicAdd(count, 1);
            if (p < MAXFLAG) list[p] = t;
        }
    } else if (blockIdx.x < 144) {
        int i = (blockIdx.x - 16) * 256 + threadIdx.x;   // 0..32767
        slot_pos[i] = -1;
        slot_val[i] = 0.f;
    }
}

// ---------------- Kernel 7a: batched exact pre-activation h for flagged --
// grid (64 f-chunks, 4 k-splits); one W1 pass per 32 flagged tokens.
__global__ __launch_bounds__(256) void fixup_stageA(
    const float* __restrict__ x, const float* __restrict__ W1,
    const int* __restrict__ count_p, const int* __restrict__ list,
    float* __restrict__ hflag)
{
    __shared__ float xs[GSIZE][256];          // 32 KB
    __shared__ float red[4][GSIZE][64];       // 32 KB
    const int tid = threadIdx.x;
    const int fl  = tid & 63;
    const int kg  = tid >> 6;
    const int f   = blockIdx.x * 64 + fl;
    const int kbase = blockIdx.y * 1024;
    int count = *count_p;
    if (count > MAXFLAG) count = MAXFLAG;

    for (int g = 0; g * GSIZE < count; ++g) {
        const int gbase = g * GSIZE;
        int ntok = count - gbase; if (ntok > GSIZE) ntok = GSIZE;

        float acc[GSIZE];
#pragma unroll
        for (int t = 0; t < GSIZE; ++t) acc[t] = 0.f;

        for (int kb = 0; kb < 1024; kb += 256) {
            __syncthreads();
            for (int i = tid; i < ntok * 256; i += 256) {
                int t = i >> 8, kk = i & 255;
                xs[t][kk] = x[(size_t)list[gbase + t] * HD + kbase + kb + kk];
            }
            __syncthreads();
            for (int j = 0; j < 64; ++j) {
                int kk = kg * 64 + j;
                float w = W1[(size_t)(kbase + kb + kk) * HD + f];
#pragma unroll
                for (int t = 0; t < GSIZE; ++t) acc[t] += xs[t][kk] * w;
            }
        }
        __syncthreads();
#pragma unroll
        for (int t = 0; t < GSIZE; ++t) red[kg][t][fl] = acc[t];
        __syncthreads();
        if (kg == 0) {
            for (int t = 0; t < ntok; ++t) {
                float v = red[0][t][fl] + red[1][t][fl] + red[2][t][fl] + red[3][t][fl];
                atomicAdd(&hflag[(size_t)(gbase + t) * HD + f], v);
            }
        }
        __syncthreads();
    }
}

// ---------------- Kernel 7b: exact logits for flagged tokens -------------
__global__ __launch_bounds__(256) void fixup_stageB(
    const float* __restrict__ hflag, const float* __restrict__ b1,
    const float* __restrict__ W2, const float* __restrict__ b2,
    const int* __restrict__ count_p, const int* __restrict__ list,
    float* __restrict__ logits)
{
    int count = *count_p;
    if (count > MAXFLAG) count = MAXFLAG;
    const int b = blockIdx.x;
    if (b >= count) return;
    const int tok = list[b];
    const int tid = threadIdx.x;

    float acc[NE];
#pragma unroll
    for (int e = 0; e < NE; ++e) acc[e] = 0.f;
    for (int f = tid; f < HD; f += 256) {
        float hv = hflag[(size_t)b * HD + f] + b1[f];
        hv = hv > 0.f ? hv : 0.f;
        float4 w0 = *(const float4*)(W2 + (size_t)f * NE);
        float4 w1 = *(const float4*)(W2 + (size_t)f * NE + 4);
        acc[0] += hv * w0.x; acc[1] += hv * w0.y; acc[2] += hv * w0.z; acc[3] += hv * w0.w;
        acc[4] += hv * w1.x; acc[5] += hv * w1.y; acc[6] += hv * w1.z; acc[7] += hv * w1.w;
    }
    __shared__ float red[256][NE];
#pragma unroll
    for (int e = 0; e < NE; ++e) red[tid][e] = acc[e];
    __syncthreads();
    for (int s = 128; s > 0; s >>= 1) {
        if (tid < s) {
#pragma unroll
            for (int e = 0; e < NE; ++e) red[tid][e] += red[tid + s][e];
        }
        __syncthreads();
    }
    if (tid < NE) logits[(size_t)tok * NE + tid] = red[0][tid] + b2[tid];
}

// ---------------- Kernel 8: softmax + top2 + renorm + partials (+hflag0) --
__global__ __launch_bounds__(256) void softmax_top2_kernel(
    const float* __restrict__ logits, float* __restrict__ probs_out,
    float* __restrict__ top2prob, int* __restrict__ top2idx,
    float* __restrict__ partial, float* __restrict__ hflag)
{
    const int tid = threadIdx.x;
    const int t = blockIdx.x * 256 + tid;

    // folded: erase hflag residue (4 MB) before scatter; runs post-stageB.
    {
        float4* hf4 = (float4*)hflag;
        int idx = blockIdx.x * 256 + tid;          // 0..4095
        float4 z = make_float4(0.f, 0.f, 0.f, 0.f);
#pragma unroll
        for (int j = 0; j < 64; ++j) hf4[(size_t)j * 4096 + idx] = z;
    }

    float l[NE];
    *(float4*)(&l[0]) = *(const float4*)(logits + (size_t)t * NE);
    *(float4*)(&l[4]) = *(const float4*)(logits + (size_t)t * NE + 4);

    float mx = l[0];
#pragma unroll
    for (int e = 1; e < NE; ++e) mx = fmaxf(mx, l[e]);
    float p[NE], sum = 0.f;
#pragma unroll
    for (int e = 0; e < NE; ++e) { p[e] = __expf(l[e] - mx); sum += p[e]; }
    float inv = 1.f / sum;
#pragma unroll
    for (int e = 0; e < NE; ++e) p[e] *= inv;

#pragma unroll
    for (int e = 0; e < NE; ++e) probs_out[(size_t)t * NE + e] = p[e];

    float b1v = -1e30f, b2v = -1e30f;
    int i1 = 0, i2 = 0;
#pragma unroll
    for (int e = 0; e < NE; ++e) {
        float v = l[e];
        if (v > b1v) { b2v = b1v; i2 = i1; b1v = v; i1 = e; }
        else if (v > b2v) { b2v = v; i2 = e; }
    }
    float p1 = 0.f, p2 = 0.f;
#pragma unroll
    for (int e = 0; e < NE; ++e) { if (e == i1) p1 = p[e]; if (e == i2) p2 = p[e]; }
    float s = p1 + p2 + 1e-8f;
    top2prob[2 * t]     = p1 / s;
    top2prob[2 * t + 1] = p2 / s;
    top2idx[2 * t]      = i1;
    top2idx[2 * t + 1]  = i2;

    __shared__ float red[256][NE];
#pragma unroll
    for (int e = 0; e < NE; ++e) red[tid][e] = p[e];
    __syncthreads();
    for (int sdx = 128; sdx > 0; sdx >>= 1) {
        if (tid < sdx) {
#pragma unroll
            for (int e = 0; e < NE; ++e) red[tid][e] += red[tid + sdx][e];
        }
        __syncthreads();
    }
    if (tid < NE) partial[blockIdx.x * NE + tid] = red[0][tid];
}

// ---------------- Kernel 9: sequential capacity scan + slot map + aux ----
// (slot arrays pre-initialized by zero_panels_kernel)
__global__ __launch_bounds__(256) void scan_dispatch_kernel(
    const int* __restrict__ top2idx, const float* __restrict__ top2prob,
    const float* __restrict__ partial, int* __restrict__ slot_pos,
    float* __restrict__ slot_val, float* __restrict__ aux_out)
{
    const int tid = threadIdx.x;
    const int ITEMS = NSEL / 256;

    int cnt[NE];
#pragma unroll
    for (int e = 0; e < NE; ++e) cnt[e] = 0;
    const int base = tid * ITEMS;
    for (int j = 0; j < ITEMS; ++j) {
        int v = top2idx[base + j];
#pragma unroll
        for (int e = 0; e < NE; ++e) cnt[e] += (v == e);
    }

    __shared__ int scnt[256][NE];
    __shared__ int tot[NE];
#pragma unroll
    for (int e = 0; e < NE; ++e) scnt[tid][e] = cnt[e];
    __syncthreads();

    if (tid < NE) {
        int run = 0;
        for (int i = 0; i < 256; ++i) {
            int c = scnt[i][tid];
            scnt[i][tid] = run;
            run += c;
        }
        tot[tid] = run;
    }
    __syncthreads();

    int off[NE];
#pragma unroll
    for (int e = 0; e < NE; ++e) off[e] = scnt[tid][e];
    for (int j = 0; j < ITEMS; ++j) {
        int item = base + j;
        int v = top2idx[item];
        int pos = 0;
#pragma unroll
        for (int e = 0; e < NE; ++e) { if (v == e) { pos = off[e]; off[e]++; } }
        if (pos < CAP) {
            int tok = item >> 1;
            slot_pos[tok * NE + v] = pos;
            slot_val[tok * NE + v] = top2prob[item];
        }
    }

    if (tid == 0) {
        float aux = 0.f;
#pragma unroll
        for (int e = 0; e < NE; ++e) {
            float pp = 0.f;
            for (int b = 0; b < 16; ++b) pp += partial[b * NE + e];
            aux += (pp / (float)NTOK) * ((float)tot[e] / (float)NSEL);
        }
        aux_out[0] = aux * (float)NE;
    }
}

// ---------------- Kernel 10: sparse scatter into zeroed outputs ----------
__global__ __launch_bounds__(256) void scatter_kernel(
    const int* __restrict__ slot_pos, const float* __restrict__ slot_val,
    float* __restrict__ out)
{
    int i = blockIdx.x * 256 + threadIdx.x;   // tok*NE + e, 0..32767
    int sp = slot_pos[i];
    if (sp >= 0) {
        out[(size_t)i * CAP + sp] = 1.0f;
        out[COMB_OFF + (size_t)i * CAP + sp] = slot_val[i];
    }
}

// ---------------- host ---------------------------------------------------
extern "C" void kernel_launch(void* const* d_in, const int* in_sizes, int n_in,
                              void* d_out, int out_size, void* d_ws, size_t ws_size,
                              hipStream_t stream)
{
    const float* x  = (const float*)d_in[0];
    const float* W1 = (const float*)d_in[1];
    const float* b1 = (const float*)d_in[2];
    const float* W2 = (const float*)d_in[3];
    const float* b2 = (const float*)d_in[4];
    float* out = (float*)d_out;

    // Staging in d_out (panel region zeroed by zero_panels after gemm; the
    // rest of dispatch+combine (320 MB) zeroed BY the gemm's folded stores,
    // incl. the hflag zone consumed by fixup then re-zeroed pre-scatter):
    ushort_t* xp  = (ushort_t*)(out);                   // fp16 panel, 32 MB
    ushort_t* wp  = (ushort_t*)(out + 8388608);         // fp16 panel, 32 MB
    float*    hflag = out + HFLAG_OFF;                  // MAXFLAG*HD (4 MB)

    // ws layout (float offsets)
    float* ws       = (float*)d_ws;
    float* logits   = ws;
    float* top2prob = ws + 32768;
    int*   top2idx  = (int*)(ws + 40960);
    float* partial  = ws + 49152;
    int*   slot_pos = (int*)(ws + 49280);
    float* slot_val = ws + 82048;
    int*   count    = (int*)(ws + 114816);
    int*   list     = (int*)(ws + 114817);

    convert_x_panel<<<dim3(128, 32), 256, 0, stream>>>(x, xp, b2, logits);
    convert_w1_panel<<<dim3(128, 32), 256, 0, stream>>>(W1, wp);
    gemm16_8phase<<<dim3(16, 16), 512, 0, stream>>>(xp, wp, b1, W2, logits, out, count);
    // panels consumed by gemm: zero the first 64 MB now (rest already zeroed
    // by the gemm's folded stores); also flag near-ties + init slot arrays
    zero_panels_kernel<<<4096, 256, 0, stream>>>(out, logits, count, list, slot_pos, slot_val);
    fixup_stageA<<<dim3(64, 4), 256, 0, stream>>>(x, W1, count, list, hflag);
    fixup_stageB<<<MAXFLAG, 256, 0, stream>>>(hflag, b1, W2, b2, count, list, logits);
    softmax_top2_kernel<<<16, 256, 0, stream>>>(logits, out + PROBS_OFF, top2prob, top2idx, partial, hflag);
    scan_dispatch_kernel<<<1, 256, 0, stream>>>(top2idx, top2prob, partial, slot_pos, slot_val, out + AUX_OFF);
    scatter_kernel<<<128, 256, 0, stream>>>(slot_pos, slot_val, out);
}

// Round 7
// 780.702 us; speedup vs baseline: 1.0797x; 1.0100x over previous
//
#include <hip/hip_runtime.h>
#include <cmath>

// Problem constants (fixed by reference setup)
#define NTOK 4096            // B*S = 2*2048
#define HD   4096            // hidden dim
#define NE   8               // experts
#define CAP  1536            // int(B*S*1.5*2/8)
#define NSEL 8192            // NTOK * TOP_K
#define TAU  2.5e-3f         // near-tie gap threshold (fp16 gemm: sigma~4.4e-4 -> 5.7 sigma)
#define MAXFLAG 256
#define GSIZE 32             // flagged tokens per W1 pass in stageA

// d_out layout (float element offsets)
#define COMB_OFF  50331648UL   // NTOK*NE*CAP
#define PROBS_OFF 100663296UL  // 2*NTOK*NE*CAP
#define AUX_OFF   100696064UL  // PROBS_OFF + NTOK*NE
#define HFLAG_OFF 25165824UL   // hflag scratch inside dispatch region (4 MB)
#define PANEL_FLOATS 16777216  // xp+wp = 64 MB at head of d_out

typedef unsigned short ushort_t;
typedef _Float16 half_t;
typedef half_t half8 __attribute__((ext_vector_type(8)));
typedef float floatx16 __attribute__((ext_vector_type(16)));

// Panel format: [group g (32 rows)][kstep ks (32 k)][2048 bytes]; 16B chunk u:
// h=u>>6, l=u&63, r=l&31, oh=l>>5 -> (row r, k=h*16+oh*8+j). Staging: lane l
// sources chunk l / 64+l -> each global_load_lds = one contiguous 1KB burst.

// ---- async 16B global->LDS (gsrc per-lane; lds dest = base+lane*16) ------
__device__ __forceinline__ void async_copy16(const void* g, void* l) {
    __builtin_amdgcn_global_load_lds(
        (const __attribute__((address_space(1))) unsigned int*)g,
        (__attribute__((address_space(3))) unsigned int*)l, 16, 0, 0);
}

// ---------------- Kernel 1: merged panel converts (+ logits=b2 init) ------
// grid (256, 32): blockIdx.x<128 -> x panels (g=bx), else W1^T panels
// (gn=bx-128). One launch instead of two.
__global__ __launch_bounds__(256) void convert_panels(
    const float* __restrict__ x, ushort_t* __restrict__ xp,
    const float* __restrict__ W1, ushort_t* __restrict__ wp,
    const float* __restrict__ b2, float* __restrict__ logits)
{
    __shared__ float sbuf[32 * 129];
    const int q = blockIdx.y, t = threadIdx.x;

    if (blockIdx.x < 128) {
        const int g = blockIdx.x;
#pragma unroll
        for (int i = 0; i < 4; ++i) {
            int idx = i * 256 + t;
            int row = idx >> 5, c4 = (idx & 31) * 4;
            float4 v = *(const float4*)(x + (size_t)(g * 32 + row) * HD + q * 128 + c4);
            *(float4*)(&sbuf[row * 128 + c4]) = v;
        }
        __syncthreads();
#pragma unroll
        for (int it = 0; it < 2; ++it) {
            int c = it * 256 + t;
            int s = c >> 7, u = c & 127;
            int h = u >> 6, l = u & 63, r = l & 31, oh = l >> 5;
            int kl = s * 32 + h * 16 + oh * 8;
            half8 h8;
#pragma unroll
            for (int j = 0; j < 8; ++j) h8[j] = (half_t)sbuf[r * 128 + kl + j];
            size_t off = ((size_t)(g * 128 + q * 4 + s)) * 1024 + u * 8;
            *(half8*)(xp + off) = h8;
        }
        // folded init: logits[t][e] = b2[e] (16 blocks cover NTOK tokens)
        if (q == 0 && g < 16) {
            int tok = g * 256 + t;
            float4 v0 = *(const float4*)b2;
            float4 v1 = *(const float4*)(b2 + 4);
            float4* dst = (float4*)(logits + (size_t)tok * NE);
            dst[0] = v0; dst[1] = v1;
        }
    } else {
        const int gn = blockIdx.x - 128;
#pragma unroll
        for (int i = 0; i < 4; ++i) {
            int idx = i * 256 + t;
            int kr = idx >> 3, c4 = (idx & 7) * 4;
            float4 v = *(const float4*)(W1 + (size_t)(q * 128 + kr) * HD + gn * 32 + c4);
            sbuf[(c4 + 0) * 129 + kr] = v.x;
            sbuf[(c4 + 1) * 129 + kr] = v.y;
            sbuf[(c4 + 2) * 129 + kr] = v.z;
            sbuf[(c4 + 3) * 129 + kr] = v.w;
        }
        __syncthreads();
#pragma unroll
        for (int it = 0; it < 2; ++it) {
            int c = it * 256 + t;
            int s = c >> 7, u = c & 127;
            int h = u >> 6, l = u & 63, r = l & 31, oh = l >> 5;
            int kl = s * 32 + h * 16 + oh * 8;
            half8 h8;
#pragma unroll
            for (int j = 0; j < 8; ++j) h8[j] = (half_t)sbuf[r * 129 + kl + j];
            size_t off = ((size_t)(gn * 128 + q * 4 + s)) * 1024 + u * 8;
            *(half8*)(wp + off) = h8;
        }
    }
}

// ---------------- Kernel 3: fused h = relu(x@W1+b1), logits += h@W2 ------
// 256x256 tile, BK=64, 8 waves (2M x 4N), 512 threads. 2 phases/K-tile,
// 16 MFMA/phase. Zero-fold REWORKED: 2 float4 stores/phase issued strictly
// AFTER the stage loads (sched_barrier(0) pins [loads][stores] order), so
// counted waits retire a store only when it is >=2 phases old (acked; no
// L2-write-ack stall at the wait -- this was round 5/6's hidden cost).
// Ledger (op-sim verified; threshold waits self-normalize per-wave extras):
//  store phases (prologue + kt<=39 P0): TW=VM8 retires [S(n-2)2, L(n-1)4]
//  kt39 P1 (first storeless): VM6 ; kt>=40: VM4  -- each retires exactly
//  the prior phase's 4 loads. 160 slabs x 2MB = 320 MB covered exactly.
// Raw s_barrier + lgkmcnt(0) + sched_barrier(0) per rule 18; setprio around
// MFMA cluster. Epilogue: logits += relu(h)*W2 via transposed LDS tile.

#define MFMA8N(A0, A1, A2, A3, B0, B1) do { \
    acc[0][0] = __builtin_amdgcn_mfma_f32_32x32x16_f16(A0, B0, acc[0][0], 0, 0, 0); \
    acc[0][1] = __builtin_amdgcn_mfma_f32_32x32x16_f16(A0, B1, acc[0][1], 0, 0, 0); \
    acc[1][0] = __builtin_amdgcn_mfma_f32_32x32x16_f16(A1, B0, acc[1][0], 0, 0, 0); \
    acc[1][1] = __builtin_amdgcn_mfma_f32_32x32x16_f16(A1, B1, acc[1][1], 0, 0, 0); \
    acc[2][0] = __builtin_amdgcn_mfma_f32_32x32x16_f16(A2, B0, acc[2][0], 0, 0, 0); \
    acc[2][1] = __builtin_amdgcn_mfma_f32_32x32x16_f16(A2, B1, acc[2][1], 0, 0, 0); \
    acc[3][0] = __builtin_amdgcn_mfma_f32_32x32x16_f16(A3, B0, acc[3][0], 0, 0, 0); \
    acc[3][1] = __builtin_amdgcn_mfma_f32_32x32x16_f16(A3, B1, acc[3][1], 0, 0, 0); \
} while (0)

#define LDA(mi, ks) (*(const half8*)&lds[cur * 32768 + ((wm * 4 + (mi)) * 2 + ((ks) >> 1)) * 1024 + ((ks) & 1) * 512 + lsrc])
#define LDB(ni, ks) (*(const half8*)&lds[cur * 32768 + 16384 + ((wn * 2 + (ni)) * 2 + ((ks) >> 1)) * 1024 + ((ks) & 1) * 512 + lsrc])

#define STAGE_A(c, kt, ksu) do { \
    const ushort_t* s_ = srcA + ((size_t)((kt) * 2 + (ksu))) * 1024; \
    ushort_t* d_ = lds + (c) * 32768 + (wave * 2 + (ksu)) * 1024; \
    async_copy16(s_, d_); async_copy16(s_ + 512, d_ + 512); \
} while (0)

#define STAGE_B(c, kt, ksu) do { \
    const ushort_t* s_ = srcB + ((size_t)((kt) * 2 + (ksu))) * 1024; \
    ushort_t* d_ = lds + (c) * 32768 + 16384 + (wave * 2 + (ksu)) * 1024; \
    async_copy16(s_, d_); async_copy16(s_ + 512, d_ + 512); \
} while (0)

#define STAGE_AB(c, kt, ksu) do { STAGE_A(c, kt, ksu); STAGE_B(c, kt, ksu); } while (0)

// 2 zero-stores (one 2 MB slab pair across the grid), guard s<160
#define ZST2(s0) do { \
    if ((s0) < 160)     zbase[(size_t)((s0))     * 131072 + zidx] = zf4; \
    if ((s0) + 1 < 160) zbase[(size_t)((s0) + 1) * 131072 + zidx] = zf4; \
} while (0)

#define STAGE_NONE do {} while (0)
#define VM8 asm volatile("s_waitcnt vmcnt(8)" ::: "memory")
#define VM6 asm volatile("s_waitcnt vmcnt(6)" ::: "memory")
#define VM4 asm volatile("s_waitcnt vmcnt(4)" ::: "memory")
#define VM0 asm volatile("s_waitcnt vmcnt(0)" ::: "memory")
#define TW_NONE do {} while (0)

#define PHASE2(ksA, ksB, STG, ZS, TW) do { \
    half8 pa0 = LDA(0, ksA), pa1 = LDA(1, ksA), pa2 = LDA(2, ksA), pa3 = LDA(3, ksA); \
    half8 pb0 = LDB(0, ksA), pb1 = LDB(1, ksA); \
    half8 qa0 = LDA(0, ksB), qa1 = LDA(1, ksB), qa2 = LDA(2, ksB), qa3 = LDA(3, ksB); \
    half8 qb0 = LDB(0, ksB), qb1 = LDB(1, ksB); \
    STG; \
    __builtin_amdgcn_sched_barrier(0); \
    ZS; \
    __builtin_amdgcn_s_barrier(); \
    asm volatile("s_waitcnt lgkmcnt(0)" ::: "memory"); \
    __builtin_amdgcn_sched_barrier(0); \
    __builtin_amdgcn_s_setprio(1); \
    MFMA8N(pa0, pa1, pa2, pa3, pb0, pb1); \
    MFMA8N(qa0, qa1, qa2, qa3, qb0, qb1); \
    __builtin_amdgcn_s_setprio(0); \
    TW; \
    __builtin_amdgcn_s_barrier(); \
    __builtin_amdgcn_sched_barrier(0); \
} while (0)

__global__ __launch_bounds__(512, 2) void gemm16_8phase(
    const ushort_t* __restrict__ Ap, const ushort_t* __restrict__ Bp,
    const float* __restrict__ bias, const float* __restrict__ W2,
    float* __restrict__ logits_out, float* __restrict__ zout,
    int* __restrict__ count_p)
{
    __shared__ __attribute__((aligned(16))) ushort_t lds[65536];  // 128 KB

    const int tid  = threadIdx.x;
    const int wave = tid >> 6;
    const int lane = tid & 63;
    const int l31  = lane & 31;
    const int lh   = lane >> 5;
    const int m0 = blockIdx.y * 256;
    const int n0 = blockIdx.x * 256;
    const int wm = wave >> 2;        // 0..1 -> rows wm*128
    const int wn = wave & 3;         // 0..3 -> cols wn*64

    // folded init: count=0 (threshold waits absorb the extra outstanding op)
    if (blockIdx.x == 0 && blockIdx.y == 0 && tid == 0) *count_p = 0;

    // zero-fold targets: floats [PANEL_FLOATS, 2*NTOK*NE*CAP) = 320 MB
    float4* zbase = (float4*)(zout + PANEL_FLOATS);
    const int zidx = ((blockIdx.y * 16 + blockIdx.x) * 512 + tid);  // 0..131071
    const float4 zf4 = make_float4(0.f, 0.f, 0.f, 0.f);

    floatx16 acc[4][2];
#pragma unroll
    for (int mi = 0; mi < 4; ++mi)
#pragma unroll
        for (int ni = 0; ni < 2; ++ni)
#pragma unroll
            for (int r = 0; r < 16; ++r) acc[mi][ni][r] = 0.f;

    const int lsrc = lane * 8;       // 16 B per lane
    const ushort_t* srcA = Ap + ((size_t)(blockIdx.y * 8 + wave)) * 128 * 1024 + lsrc;
    const ushort_t* srcB = Bp + ((size_t)(blockIdx.x * 8 + wave)) * 128 * 1024 + lsrc;

    // Prologue: stage tile 0 (8 loads) then 2 stores; VM4 leaves
    // [ksu1_2, S2] outstanding -> kt0 P0 enters at steady-state shape.
    STAGE_AB(0, 0, 0);
    STAGE_AB(0, 0, 1);
    __builtin_amdgcn_sched_barrier(0);
    ZST2(0);
    VM4;
    __builtin_amdgcn_s_barrier();
    __builtin_amdgcn_sched_barrier(0);

    int cur = 0;
    for (int kt = 0; kt < 39; ++kt) {
        PHASE2(0, 1, STAGE_AB(cur ^ 1, kt + 1, 0), ZST2(4 * kt + 2), VM8);
        PHASE2(2, 3, STAGE_AB(cur ^ 1, kt + 1, 1), ZST2(4 * kt + 4), VM8);
        cur ^= 1;
    }
    // kt=39: last store pair {158,159}; P1 transitions to storeless ledger.
    PHASE2(0, 1, STAGE_AB(cur ^ 1, 40, 0), ZST2(158), VM8);
    PHASE2(2, 3, STAGE_AB(cur ^ 1, 40, 1), STAGE_NONE, VM6);
    cur ^= 1;
    for (int kt = 40; kt < 63; ++kt) {
        PHASE2(0, 1, STAGE_AB(cur ^ 1, kt + 1, 0), STAGE_NONE, VM4);
        PHASE2(2, 3, STAGE_AB(cur ^ 1, kt + 1, 1), STAGE_NONE, VM4);
        cur ^= 1;
    }
    // Peeled last K-tile (kt=63): no prefetch; single drain before ksu1 read.
    PHASE2(0, 1, STAGE_NONE, STAGE_NONE, VM0);
    PHASE2(2, 3, STAGE_NONE, STAGE_NONE, TW_NONE);

    // ---- fused logits epilogue (reuses the 128 KB LDS; all loads drained,
    // final phase barrier passed => safe to overwrite) --------------------
    // Ls_T[col 0..255][row 0..63] pad 65 (floats 0..16639)
    // W2s[256][8]                       (floats 16640..18687)
    // Rs[wave][64][8] pad 9             (floats 18688..23295)
    float* Lf  = (float*)lds;
    float* W2s = Lf + 16640;
    float* Rs  = Lf + 18688;

    // cache W2 slice for this block's 256 columns: 2048 floats, contiguous
    ((float4*)W2s)[tid] = ((const float4*)(W2 + (size_t)n0 * NE))[tid];

    const int ncol = n0 + wn * 64 + l31;
    const float b1v0 = bias[ncol];
    const float b1v1 = bias[ncol + 32];
    const int lcol = wn * 64 + l31;
    const int lrow_base = wm * 32;

    for (int mi = 0; mi < 4; ++mi) {
        __syncthreads();   // prev mi consumed (and W2s visible on first iter)
#pragma unroll
        for (int r = 0; r < 16; ++r) {
            int lr = lrow_base + (r & 3) + 8 * (r >> 2) + 4 * lh;
            float v0 = acc[mi][0][r] + b1v0;
            float v1 = acc[mi][1][r] + b1v1;
            Lf[(lcol)      * 65 + lr] = v0 > 0.f ? v0 : 0.f;
            Lf[(lcol + 32) * 65 + lr] = v1 > 0.f ? v1 : 0.f;
        }
        __syncthreads();
        // wave w reduces cols w*32..+31 over all 64 rows (lane = row)
        float le[NE];
#pragma unroll
        for (int e = 0; e < NE; ++e) le[e] = 0.f;
        for (int c = 0; c < 32; ++c) {
            int col = wave * 32 + c;
            float hv = Lf[col * 65 + lane];
            float4 wa = *(const float4*)&W2s[col * 8];
            float4 wb = *(const float4*)&W2s[col * 8 + 4];
            le[0] += hv * wa.x; le[1] += hv * wa.y; le[2] += hv * wa.z; le[3] += hv * wa.w;
            le[4] += hv * wb.x; le[5] += hv * wb.y; le[6] += hv * wb.z; le[7] += hv * wb.w;
        }
#pragma unroll
        for (int e = 0; e < NE; ++e) Rs[(wave * 64 + lane) * 9 + e] = le[e];
        __syncthreads();
        {
            int rr = tid >> 3, e = tid & 7;      // 512 threads = 64 rows x 8 e
            float s = 0.f;
#pragma unroll
            for (int w = 0; w < 8; ++w) s += Rs[(w * 64 + rr) * 9 + e];
            int row_g = m0 + (rr >> 5) * 128 + mi * 32 + (rr & 31);
            atomicAdd(&logits_out[(size_t)row_g * NE + e], s);
        }
    }
}

// ---------------- Kernel 4: zero panels + flag near-ties + slot init -----
// 4096 blocks: all zero the 64 MB panel region; blocks 0-15 additionally
// run flag_compact (count was zeroed by the gemm); blocks 16-143 init the
// slot_pos/slot_val arrays (removed from the serial scan kernel).
__global__ __launch_bounds__(256) void zero_panels_kernel(
    float* __restrict__ out, const float* __restrict__ logits,
    int* __restrict__ count, int* __restrict__ list,
    int* __restrict__ slot_pos, float* __restrict__ slot_val)
{
    const int TOTALQ = PANEL_FLOATS / 4;   // 4194304 float4
    int stride = gridDim.x * 256;
    float4 z = make_float4(0.f, 0.f, 0.f, 0.f);
    for (int q = blockIdx.x * 256 + threadIdx.x; q < TOTALQ; q += stride)
        ((float4*)out)[q] = z;

    if (blockIdx.x < 16) {
        int t = blockIdx.x * 256 + threadIdx.x;
        float l[NE];
        *(float4*)(&l[0]) = *(const float4*)(logits + (size_t)t * NE);
        *(float4*)(&l[4]) = *(const float4*)(logits + (size_t)t * NE + 4);
        float a = -1e30f, b = -1e30f, c = -1e30f;
#pragma unroll
        for (int e = 0; e < NE; ++e) {
            float v = l[e];
            if (v > a) { c = b; b = a; a = v; }
            else if (v > b) { c = b; b = v; }
            else if (v > c) { c = v; }
        }
        if (b - c < TAU) {
            int p = atomicAdd(count, 1);
            if (p < MAXFLAG) list[p] = t;
        }
    } else if (blockIdx.x < 144) {
        int i = (blockIdx.x - 16) * 256 + threadIdx.x;   // 0..32767
        slot_pos[i] = -1;
        slot_val[i] = 0.f;
    }
}

// ---------------- Kernel 7a: batched exact pre-activation h for flagged --
// grid (64 f-chunks, 4 k-splits); one W1 pass per 32 flagged tokens.
__global__ __launch_bounds__(256) void fixup_stageA(
    const float* __restrict__ x, const float* __restrict__ W1,
    const int* __restrict__ count_p, const int* __restrict__ list,
    float* __restrict__ hflag)
{
    __shared__ float xs[GSIZE][256];          // 32 KB
    __shared__ float red[4][GSIZE][64];       // 32 KB
    const int tid = threadIdx.x;
    const int fl  = tid & 63;
    const int kg  = tid >> 6;
    const int f   = blockIdx.x * 64 + fl;
    const int kbase = blockIdx.y * 1024;
    int count = *count_p;
    if (count > MAXFLAG) count = MAXFLAG;

    for (int g = 0; g * GSIZE < count; ++g) {
        const int gbase = g * GSIZE;
        int ntok = count - gbase; if (ntok > GSIZE) ntok = GSIZE;

        float acc[GSIZE];
#pragma unroll
        for (int t = 0; t < GSIZE; ++t) acc[t] = 0.f;

        for (int kb = 0; kb < 1024; kb += 256) {
            __syncthreads();
            for (int i = tid; i < ntok * 256; i += 256) {
                int t = i >> 8, kk = i & 255;
                xs[t][kk] = x[(size_t)list[gbase + t] * HD + kbase + kb + kk];
            }
            __syncthreads();
            for (int j = 0; j < 64; ++j) {
                int kk = kg * 64 + j;
                float w = W1[(size_t)(kbase + kb + kk) * HD + f];
#pragma unroll
                for (int t = 0; t < GSIZE; ++t) acc[t] += xs[t][kk] * w;
            }
        }
        __syncthreads();
#pragma unroll
        for (int t = 0; t < GSIZE; ++t) red[kg][t][fl] = acc[t];
        __syncthreads();
        if (kg == 0) {
            for (int t = 0; t < ntok; ++t) {
                float v = red[0][t][fl] + red[1][t][fl] + red[2][t][fl] + red[3][t][fl];
                atomicAdd(&hflag[(size_t)(gbase + t) * HD + f], v);
            }
        }
        __syncthreads();
    }
}

// ---------------- Kernel 7b: exact logits for flagged tokens -------------
__global__ __launch_bounds__(256) void fixup_stageB(
    const float* __restrict__ hflag, const float* __restrict__ b1,
    const float* __restrict__ W2, const float* __restrict__ b2,
    const int* __restrict__ count_p, const int* __restrict__ list,
    float* __restrict__ logits)
{
    int count = *count_p;
    if (count > MAXFLAG) count = MAXFLAG;
    const int b = blockIdx.x;
    if (b >= count) return;
    const int tok = list[b];
    const int tid = threadIdx.x;

    float acc[NE];
#pragma unroll
    for (int e = 0; e < NE; ++e) acc[e] = 0.f;
    for (int f = tid; f < HD; f += 256) {
        float hv = hflag[(size_t)b * HD + f] + b1[f];
        hv = hv > 0.f ? hv : 0.f;
        float4 w0 = *(const float4*)(W2 + (size_t)f * NE);
        float4 w1 = *(const float4*)(W2 + (size_t)f * NE + 4);
        acc[0] += hv * w0.x; acc[1] += hv * w0.y; acc[2] += hv * w0.z; acc[3] += hv * w0.w;
        acc[4] += hv * w1.x; acc[5] += hv * w1.y; acc[6] += hv * w1.z; acc[7] += hv * w1.w;
    }
    __shared__ float red[256][NE];
#pragma unroll
    for (int e = 0; e < NE; ++e) red[tid][e] = acc[e];
    __syncthreads();
    for (int s = 128; s > 0; s >>= 1) {
        if (tid < s) {
#pragma unroll
            for (int e = 0; e < NE; ++e) red[tid][e] += red[tid + s][e];
        }
        __syncthreads();
    }
    if (tid < NE) logits[(size_t)tok * NE + tid] = red[0][tid] + b2[tid];
}

// ---------------- Kernel 8: softmax + top2 + renorm + partials (+hflag0) --
__global__ __launch_bounds__(256) void softmax_top2_kernel(
    const float* __restrict__ logits, float* __restrict__ probs_out,
    float* __restrict__ top2prob, int* __restrict__ top2idx,
    float* __restrict__ partial, float* __restrict__ hflag)
{
    const int tid = threadIdx.x;
    const int t = blockIdx.x * 256 + tid;

    // folded: erase hflag residue (4 MB) before scatter; runs post-stageB.
    {
        float4* hf4 = (float4*)hflag;
        int idx = blockIdx.x * 256 + tid;          // 0..4095
        float4 z = make_float4(0.f, 0.f, 0.f, 0.f);
#pragma unroll
        for (int j = 0; j < 64; ++j) hf4[(size_t)j * 4096 + idx] = z;
    }

    float l[NE];
    *(float4*)(&l[0]) = *(const float4*)(logits + (size_t)t * NE);
    *(float4*)(&l[4]) = *(const float4*)(logits + (size_t)t * NE + 4);

    float mx = l[0];
#pragma unroll
    for (int e = 1; e < NE; ++e) mx = fmaxf(mx, l[e]);
    float p[NE], sum = 0.f;
#pragma unroll
    for (int e = 0; e < NE; ++e) { p[e] = __expf(l[e] - mx); sum += p[e]; }
    float inv = 1.f / sum;
#pragma unroll
    for (int e = 0; e < NE; ++e) p[e] *= inv;

#pragma unroll
    for (int e = 0; e < NE; ++e) probs_out[(size_t)t * NE + e] = p[e];

    float b1v = -1e30f, b2v = -1e30f;
    int i1 = 0, i2 = 0;
#pragma unroll
    for (int e = 0; e < NE; ++e) {
        float v = l[e];
        if (v > b1v) { b2v = b1v; i2 = i1; b1v = v; i1 = e; }
        else if (v > b2v) { b2v = v; i2 = e; }
    }
    float p1 = 0.f, p2 = 0.f;
#pragma unroll
    for (int e = 0; e < NE; ++e) { if (e == i1) p1 = p[e]; if (e == i2) p2 = p[e]; }
    float s = p1 + p2 + 1e-8f;
    top2prob[2 * t]     = p1 / s;
    top2prob[2 * t + 1] = p2 / s;
    top2idx[2 * t]      = i1;
    top2idx[2 * t + 1]  = i2;

    __shared__ float red[256][NE];
#pragma unroll
    for (int e = 0; e < NE; ++e) red[tid][e] = p[e];
    __syncthreads();
    for (int sdx = 128; sdx > 0; sdx >>= 1) {
        if (tid < sdx) {
#pragma unroll
            for (int e = 0; e < NE; ++e) red[tid][e] += red[tid + sdx][e];
        }
        __syncthreads();
    }
    if (tid < NE) partial[blockIdx.x * NE + tid] = red[0][tid];
}

// ---------------- Kernel 9: sequential capacity scan + slot map + aux ----
// (slot arrays pre-initialized by zero_panels_kernel)
__global__ __launch_bounds__(256) void scan_dispatch_kernel(
    const int* __restrict__ top2idx, const float* __restrict__ top2prob,
    const float* __restrict__ partial, int* __restrict__ slot_pos,
    float* __restrict__ slot_val, float* __restrict__ aux_out)
{
    const int tid = threadIdx.x;
    const int ITEMS = NSEL / 256;

    int cnt[NE];
#pragma unroll
    for (int e = 0; e < NE; ++e) cnt[e] = 0;
    const int base = tid * ITEMS;
    for (int j = 0; j < ITEMS; ++j) {
        int v = top2idx[base + j];
#pragma unroll
        for (int e = 0; e < NE; ++e) cnt[e] += (v == e);
    }

    __shared__ int scnt[256][NE];
    __shared__ int tot[NE];
#pragma unroll
    for (int e = 0; e < NE; ++e) scnt[tid][e] = cnt[e];
    __syncthreads();

    if (tid < NE) {
        int run = 0;
        for (int i = 0; i < 256; ++i) {
            int c = scnt[i][tid];
            scnt[i][tid] = run;
            run += c;
        }
        tot[tid] = run;
    }
    __syncthreads();

    int off[NE];
#pragma unroll
    for (int e = 0; e < NE; ++e) off[e] = scnt[tid][e];
    for (int j = 0; j < ITEMS; ++j) {
        int item = base + j;
        int v = top2idx[item];
        int pos = 0;
#pragma unroll
        for (int e = 0; e < NE; ++e) { if (v == e) { pos = off[e]; off[e]++; } }
        if (pos < CAP) {
            int tok = item >> 1;
            slot_pos[tok * NE + v] = pos;
            slot_val[tok * NE + v] = top2prob[item];
        }
    }

    if (tid == 0) {
        float aux = 0.f;
#pragma unroll
        for (int e = 0; e < NE; ++e) {
            float pp = 0.f;
            for (int b = 0; b < 16; ++b) pp += partial[b * NE + e];
            aux += (pp / (float)NTOK) * ((float)tot[e] / (float)NSEL);
        }
        aux_out[0] = aux * (float)NE;
    }
}

// ---------------- Kernel 10: sparse scatter into zeroed outputs ----------
__global__ __launch_bounds__(256) void scatter_kernel(
    const int* __restrict__ slot_pos, const float* __restrict__ slot_val,
    float* __restrict__ out)
{
    int i = blockIdx.x * 256 + threadIdx.x;   // tok*NE + e, 0..32767
    int sp = slot_pos[i];
    if (sp >= 0) {
        out[(size_t)i * CAP + sp] = 1.0f;
        out[COMB_OFF + (size_t)i * CAP + sp] = slot_val[i];
    }
}

// ---------------- host ---------------------------------------------------
extern "C" void kernel_launch(void* const* d_in, const int* in_sizes, int n_in,
                              void* d_out, int out_size, void* d_ws, size_t ws_size,
                              hipStream_t stream)
{
    const float* x  = (const float*)d_in[0];
    const float* W1 = (const float*)d_in[1];
    const float* b1 = (const float*)d_in[2];
    const float* W2 = (const float*)d_in[3];
    const float* b2 = (const float*)d_in[4];
    float* out = (float*)d_out;

    // Staging in d_out (panel region zeroed by zero_panels after gemm; the
    // rest of dispatch+combine (320 MB) zeroed BY the gemm's folded stores,
    // incl. the hflag zone consumed by fixup then re-zeroed pre-scatter):
    ushort_t* xp  = (ushort_t*)(out);                   // fp16 panel, 32 MB
    ushort_t* wp  = (ushort_t*)(out + 8388608);         // fp16 panel, 32 MB
    float*    hflag = out + HFLAG_OFF;                  // MAXFLAG*HD (4 MB)

    // ws layout (float offsets)
    float* ws       = (float*)d_ws;
    float* logits   = ws;
    float* top2prob = ws + 32768;
    int*   top2idx  = (int*)(ws + 40960);
    float* partial  = ws + 49152;
    int*   slot_pos = (int*)(ws + 49280);
    float* slot_val = ws + 82048;
    int*   count    = (int*)(ws + 114816);
    int*   list     = (int*)(ws + 114817);

    convert_panels<<<dim3(256, 32), 256, 0, stream>>>(x, xp, W1, wp, b2, logits);
    gemm16_8phase<<<dim3(16, 16), 512, 0, stream>>>(xp, wp, b1, W2, logits, out, count);
    // panels consumed by gemm: zero the first 64 MB now (rest already zeroed
    // by the gemm's folded stores); also flag near-ties + init slot arrays
    zero_panels_kernel<<<4096, 256, 0, stream>>>(out, logits, count, list, slot_pos, slot_val);
    fixup_stageA<<<dim3(64, 4), 256, 0, stream>>>(x, W1, count, list, hflag);
    fixup_stageB<<<MAXFLAG, 256, 0, stream>>>(hflag, b1, W2, b2, count, list, logits);
    softmax_top2_kernel<<<16, 256, 0, stream>>>(logits, out + PROBS_OFF, top2prob, top2idx, partial, hflag);
    scan_dispatch_kernel<<<1, 256, 0, stream>>>(top2idx, top2prob, partial, slot_pos, slot_val, out + AUX_OFF);
    scatter_kernel<<<128, 256, 0, stream>>>(slot_pos, slot_val, out);
}